// Round 3
// baseline (1298.990 us; speedup 1.0000x reference)
//
#include <hip/hip_runtime.h>
#include <cstdint>
#include <cstddef>

#define D 128
#define RR 8

typedef __attribute__((ext_vector_type(8))) short short8;
typedef __attribute__((ext_vector_type(4))) float f32x4;
typedef __attribute__((ext_vector_type(4))) unsigned short ushort4v;

__device__ inline ushort f2b(float x) {
    union { float f; unsigned u; } v; v.f = x;
    unsigned r = v.u + 0x7fff + ((v.u >> 16) & 1);
    return (ushort)(r >> 16);
}
__device__ inline float b2f(ushort u) {
    union { unsigned u; float f; } v; v.u = ((unsigned)u) << 16; return v.f;
}

// async global->LDS, 16B per lane; LDS dest = wave-uniform base + lane*16
__device__ inline void gload_lds16(const ushort* g, ushort* l) {
    __builtin_amdgcn_global_load_lds(
        (const __attribute__((address_space(1))) unsigned int*)g,
        (__attribute__((address_space(3))) unsigned int*)l, 16, 0, 0);
}

// ---------------------------------------------------------------------------
// bf16 MFMA GEMM with SPLIT A: C[M, ncol] = [A0 | A1] @ B (+bias) (+relu)
// K-steps 0..k0steps-1 read A0 (lda0), steps k0steps.. read A1 (lda1).
// BT: [128][ktiles*128] bf16, row = out col.  256 thr = 4 waves; tile 128x128;
// BK=64 (32 KB LDS -> 4 blocks/CU).  global_load_lds width=16, LDS linear,
// XOR bank swizzle applied on per-lane GLOBAL source addr + ds_read addr.
// OOB tail rows clamp to row M-1 (valid memory; never stored).
// In-place A==Cb safe (block only reads/writes its own rows).
// ---------------------------------------------------------------------------
template<bool BIAS, bool RELU, bool STF, bool STB>
__global__ __launch_bounds__(256, 4) void gemm_bf16(
    const ushort* __restrict__ A0, int lda0, int k0steps,
    const ushort* __restrict__ A1, int lda1,
    const ushort* __restrict__ BT, int ktiles,
    const float* __restrict__ bias, float* __restrict__ Cf, int ldcf,
    ushort* __restrict__ Cb, int ldcb, int M, int ncol)
{
    __shared__ ushort As[128 * 64];
    __shared__ ushort Bs[128 * 64];
    const int tid = threadIdx.x;
    const int m0 = blockIdx.x * 128;
    const int ldb = ktiles * 128;
    const int ksteps = ktiles * 2;          // BK = 64

    const int w = tid >> 6, lane = tid & 63;
    const int wm = (w & 1) * 64, wn = (w >> 1) * 64;
    const int l15 = lane & 15, quad = lane >> 4;

    // staging geometry: per (wave, it) the wave fills LDS groups
    // gi = w*256 + it*64 + lane ; row = gi>>3, g = gi&7 (8 x 16B groups/row).
    // Data at linear LDS group (row,g) comes from global col-group g^(row&7).
    const ushort* a0p[4];
    const ushort* a1p[4];
    const ushort* bp[4];
#pragma unroll
    for (int it = 0; it < 4; it++) {
        int gi = w * 256 + it * 64 + lane;
        int row = gi >> 3, g = gi & 7;
        int cg = g ^ (row & 7);
        int gr = m0 + row; if (gr > M - 1) gr = M - 1;   // clamp tail
        a0p[it] = A0 + (size_t)gr * lda0 + (cg << 3);
        a1p[it] = A1 + (size_t)gr * lda1 + (cg << 3);
        bp[it]  = BT + (size_t)row * ldb + (cg << 3);    // B rows 0..127 always valid
    }

    f32x4 acc[4][4];
    const f32x4 z4 = {0.f, 0.f, 0.f, 0.f};
#pragma unroll
    for (int i = 0; i < 4; i++)
#pragma unroll
        for (int j = 0; j < 4; j++) acc[i][j] = z4;

    for (int kt = 0; kt < ksteps; kt++) {
        const int ko = kt * 64;
        if (kt < k0steps) {
#pragma unroll
            for (int it = 0; it < 4; it++)
                gload_lds16(a0p[it] + ko, As + w * 2048 + it * 512);
        } else {
            const int ko1 = (kt - k0steps) * 64;
#pragma unroll
            for (int it = 0; it < 4; it++)
                gload_lds16(a1p[it] + ko1, As + w * 2048 + it * 512);
        }
#pragma unroll
        for (int it = 0; it < 4; it++)
            gload_lds16(bp[it] + ko, Bs + w * 2048 + it * 512);
        __syncthreads();   // compiler emits vmcnt(0) drain before barrier

#pragma unroll
        for (int ks = 0; ks < 64; ks += 32) {
            const int q0 = (ks >> 3) + quad;        // k-group 0..7
            short8 af[4], bfr[4];
#pragma unroll
            for (int i = 0; i < 4; i++) {
                int row = wm + i * 16 + l15;
                af[i] = *(const short8*)(&As[row * 64 + ((q0 ^ (row & 7)) << 3)]);
            }
#pragma unroll
            for (int j = 0; j < 4; j++) {
                int row = wn + j * 16 + l15;
                bfr[j] = *(const short8*)(&Bs[row * 64 + ((q0 ^ (row & 7)) << 3)]);
            }
#pragma unroll
            for (int i = 0; i < 4; i++)
#pragma unroll
                for (int j = 0; j < 4; j++)
                    acc[i][j] = __builtin_amdgcn_mfma_f32_16x16x32_bf16(
                        af[i], bfr[j], acc[i][j], 0, 0, 0);
        }
        __syncthreads();
    }

    // epilogue: C[m=quad*4+q][n=l15] per 16x16 frag
#pragma unroll
    for (int i = 0; i < 4; i++) {
#pragma unroll
        for (int q = 0; q < 4; q++) {
            int gm = m0 + wm + i * 16 + quad * 4 + q;
            if (gm >= M) continue;
#pragma unroll
            for (int j = 0; j < 4; j++) {
                int gn = wn + j * 16 + l15;
                if (gn >= ncol) continue;
                float v = acc[i][j][q];
                if (BIAS) v += bias[gn];
                if (RELU) v = v > 0.f ? v : 0.f;
                if (STF) Cf[(size_t)gm * ldcf + gn] = v;
                if (STB) Cb[(size_t)gm * ldcb + gn] = f2b(v);
            }
        }
    }
}

// ---------------------------------------------------------------------------
// bigBT[f][c]: c<1024 -> W_{c>>7}[c&127][f];  c>=1024 -> root[c-1024][f]
// ---------------------------------------------------------------------------
__global__ void build_bigBT(const float* __restrict__ basis,
                            const float* __restrict__ comp,
                            const float* __restrict__ root,
                            ushort* __restrict__ BT)
{
    int i = blockIdx.x * 256 + threadIdx.x;
    if (i >= 128 * 1152) return;
    int f = i / 1152, c = i - f * 1152;
    float a;
    if (c < 1024) {
        int r = c >> 7, d = c & 127;
        a = 0.f;
#pragma unroll
        for (int b = 0; b < 4; b++)
            a += comp[r * 4 + b] * basis[(b * 128 + d) * 128 + f];
    } else {
        a = root[(c - 1024) * 128 + f];
    }
    BT[i] = f2b(a);
}

// out[f*128+k] = bf16(in[k*cols+f]) for f<cols else 0   (in: [128][cols])
__global__ void transpose_pad(const float* __restrict__ in, ushort* __restrict__ out,
                              int cols)
{
    int i = blockIdx.x * 256 + threadIdx.x;
    if (i >= 128 * 128) return;
    int k = i & 127, f = i >> 7;
    out[i] = (f < cols) ? f2b(in[k * cols + f]) : (ushort)0;
}

// x [N][128] fp32 -> compact bf16 Hc [N][128]
__global__ void cast_x(const float* __restrict__ in, ushort* __restrict__ Hc, int total4)
{
    int i = blockIdx.x * 256 + threadIdx.x;
    if (i >= total4) return;
    float4 v = ((const float4*)in)[i];
    ushort4 o = { f2b(v.x), f2b(v.y), f2b(v.z), f2b(v.w) };
    *(ushort4*)(Hc + (size_t)i * 4) = o;
}

// ---------------------------------------------------------------------------
__global__ void count_edges(const int* __restrict__ src, const int* __restrict__ dst,
                            const int* __restrict__ et, int* __restrict__ cnt,
                            int* __restrict__ deg, int E)
{
    int t = blockIdx.x * 256 + threadIdx.x;
    int e0 = t * 4;
    if (e0 + 4 <= E) {
        int4 s4 = ((const int4*)src)[t];
        int4 d4 = ((const int4*)dst)[t];
        int4 t4 = ((const int4*)et)[t];
        atomicAdd(&cnt[d4.x * RR + t4.x], 1); atomicAdd(&deg[s4.x], 1);
        atomicAdd(&cnt[d4.y * RR + t4.y], 1); atomicAdd(&deg[s4.y], 1);
        atomicAdd(&cnt[d4.z * RR + t4.z], 1); atomicAdd(&deg[s4.z], 1);
        atomicAdd(&cnt[d4.w * RR + t4.w], 1); atomicAdd(&deg[s4.w], 1);
    } else {
        for (int e = e0; e < E; e++) {
            atomicAdd(&cnt[dst[e] * RR + et[e]], 1);
            atomicAdd(&deg[src[e]], 1);
        }
    }
}

// ---------------------------------------------------------------------------
// 3-phase exclusive scan (1024 elements per block)
// ---------------------------------------------------------------------------
__global__ void scan1(const int* __restrict__ in, int* __restrict__ bsum, int n)
{
    __shared__ int s[256];
    const int b = blockIdx.x, t = threadIdx.x;
    const int base = b * 1024;
    int v = 0;
#pragma unroll
    for (int i = 0; i < 4; i++) {
        int idx = base + t * 4 + i;
        if (idx < n) v += in[idx];
    }
    s[t] = v; __syncthreads();
    for (int off = 128; off > 0; off >>= 1) {
        if (t < off) s[t] += s[t + off];
        __syncthreads();
    }
    if (t == 0) bsum[b] = s[0];
}

__global__ void scan_top(int* __restrict__ bsum, int nb)
{
    __shared__ int s[1024];
    const int t = threadIdx.x;
    int v = (t < nb) ? bsum[t] : 0;
    s[t] = v; __syncthreads();
    for (int off = 1; off < 1024; off <<= 1) {
        int x = (t >= off) ? s[t - off] : 0;
        __syncthreads();
        s[t] += x;
        __syncthreads();
    }
    if (t < nb) bsum[t] = s[t] - v;   // exclusive
}

__global__ void scan2(const int* __restrict__ in, const int* __restrict__ bsum,
                      int* __restrict__ out, int n)
{
    __shared__ int s[256];
    const int b = blockIdx.x, t = threadIdx.x;
    const int base = b * 1024;
    int loc[4];
    int v = 0;
#pragma unroll
    for (int i = 0; i < 4; i++) {
        int idx = base + t * 4 + i;
        int x = (idx < n) ? in[idx] : 0;
        loc[i] = v; v += x;
    }
    s[t] = v; __syncthreads();
    for (int off = 1; off < 256; off <<= 1) {
        int x = (t >= off) ? s[t - off] : 0;
        __syncthreads();
        s[t] += x;
        __syncthreads();
    }
    const int add = bsum[b] + (s[t] - v);
#pragma unroll
    for (int i = 0; i < 4; i++) {
        int idx = base + t * 4 + i;
        if (idx < n) out[idx] = add + loc[i];
    }
}

// copy offsets into the atomic cursors (acur <- aoff, gcur <- goff)
__global__ void copy_off(const int* __restrict__ aoff, int* __restrict__ acur, int na,
                         const int* __restrict__ goff, int* __restrict__ gcur, int ng)
{
    int i = blockIdx.x * 256 + threadIdx.x;
    if (i < na) acur[i] = aoff[i];
    if (i < ng) gcur[i] = goff[i];
}

// ---------------------------------------------------------------------------
// both CSR fills in one pass; cursors pre-seeded with offsets, atomicAdd
// returns the slot directly (no separate random aoff/goff reads).
// ---------------------------------------------------------------------------
__global__ void fill_both(const int* __restrict__ src, const int* __restrict__ dst,
                          const int* __restrict__ et,
                          int* __restrict__ acur, int* __restrict__ acsr,
                          int* __restrict__ gcur, int* __restrict__ gcsr, int E)
{
    int t = blockIdx.x * 256 + threadIdx.x;
    int e0 = t * 4;
    if (e0 + 4 <= E) {
        int4 s4 = ((const int4*)src)[t];
        int4 d4 = ((const int4*)dst)[t];
        int4 t4 = ((const int4*)et)[t];
        int p;
        p = atomicAdd(&acur[d4.x * RR + t4.x], 1); acsr[p] = s4.x;
        p = atomicAdd(&acur[d4.y * RR + t4.y], 1); acsr[p] = s4.y;
        p = atomicAdd(&acur[d4.z * RR + t4.z], 1); acsr[p] = s4.z;
        p = atomicAdd(&acur[d4.w * RR + t4.w], 1); acsr[p] = s4.w;
        p = atomicAdd(&gcur[s4.x], 1); gcsr[p] = d4.x;
        p = atomicAdd(&gcur[s4.y], 1); gcsr[p] = d4.y;
        p = atomicAdd(&gcur[s4.z], 1); gcsr[p] = d4.z;
        p = atomicAdd(&gcur[s4.w], 1); gcsr[p] = d4.w;
    } else {
        for (int e = e0; e < E; e++) {
            int s0 = src[e], d0 = dst[e];
            int p = atomicAdd(&acur[d0 * RR + et[e]], 1);
            acsr[p] = s0;
            int pg = atomicAdd(&gcur[s0], 1);
            gcsr[pg] = d0;
        }
    }
}

// ---------------------------------------------------------------------------
// gate gather (compact bf16 Hc): TAUb[n] = bf16(tanh( mean_out (h[n]-h[dst])^2 ))
// 4-unrolled neighbor loop for memory-level parallelism.
// ---------------------------------------------------------------------------
__global__ __launch_bounds__(256) void gate_gather(
    const ushort* __restrict__ Hc, const int* __restrict__ gcsr,
    const int* __restrict__ goff, const int* __restrict__ deg,
    ushort* __restrict__ TAUb, int N)
{
    const int g = threadIdx.x >> 5, lane = threadIdx.x & 31;
    const int n = blockIdx.x * 8 + g;
    if (n >= N) return;
    const int start = goff[n];
    const int c = deg[n];
    const ushort* hbase = Hc + lane * 4;
    ushort4 a4 = *(const ushort4*)(hbase + (size_t)n * 128);
    float ax = b2f(a4.x), ay = b2f(a4.y), az = b2f(a4.z), aw = b2f(a4.w);
    float4 acc = {0.f, 0.f, 0.f, 0.f};
    int i = 0;
    for (; i + 4 <= c; i += 4) {
        int d0 = gcsr[start + i],     d1 = gcsr[start + i + 1];
        int d2 = gcsr[start + i + 2], d3 = gcsr[start + i + 3];
        ushort4 b0 = *(const ushort4*)(hbase + (size_t)d0 * 128);
        ushort4 b1 = *(const ushort4*)(hbase + (size_t)d1 * 128);
        ushort4 b2 = *(const ushort4*)(hbase + (size_t)d2 * 128);
        ushort4 b3 = *(const ushort4*)(hbase + (size_t)d3 * 128);
        float dx, dy, dz, dw;
        dx = ax - b2f(b0.x); dy = ay - b2f(b0.y); dz = az - b2f(b0.z); dw = aw - b2f(b0.w);
        acc.x += dx * dx; acc.y += dy * dy; acc.z += dz * dz; acc.w += dw * dw;
        dx = ax - b2f(b1.x); dy = ay - b2f(b1.y); dz = az - b2f(b1.z); dw = aw - b2f(b1.w);
        acc.x += dx * dx; acc.y += dy * dy; acc.z += dz * dz; acc.w += dw * dw;
        dx = ax - b2f(b2.x); dy = ay - b2f(b2.y); dz = az - b2f(b2.z); dw = aw - b2f(b2.w);
        acc.x += dx * dx; acc.y += dy * dy; acc.z += dz * dz; acc.w += dw * dw;
        dx = ax - b2f(b3.x); dy = ay - b2f(b3.y); dz = az - b2f(b3.z); dw = aw - b2f(b3.w);
        acc.x += dx * dx; acc.y += dy * dy; acc.z += dz * dz; acc.w += dw * dw;
    }
    for (; i < c; i++) {
        int d0 = gcsr[start + i];
        ushort4 b0 = *(const ushort4*)(hbase + (size_t)d0 * 128);
        float dx = ax - b2f(b0.x), dy = ay - b2f(b0.y),
              dz = az - b2f(b0.z), dw = aw - b2f(b0.w);
        acc.x += dx * dx; acc.y += dy * dy; acc.z += dz * dz; acc.w += dw * dw;
    }
    const float inv = (c > 0) ? (1.f / (float)c) : 1.f;
    ushort4 t;
    t.x = f2b(tanhf(acc.x * inv)); t.y = f2b(tanhf(acc.y * inv));
    t.z = f2b(tanhf(acc.z * inv)); t.w = f2b(tanhf(acc.w * inv));
    *(ushort4*)(TAUb + (size_t)n * D + lane * 4) = t;
}

// ---------------------------------------------------------------------------
// agg gather, NODE-per-group: one 32-lane group walks all 8 relation segments
// of node n (contiguous in acsr since segments n*8+r are adjacent).  Amortizes
// meta reads over ~16 edges instead of ~2; acsr stream sequential; 4-unrolled
// row loads.  Output NT-stored (write stream must not evict Hc from L2/L3).
// ---------------------------------------------------------------------------
__global__ __launch_bounds__(256) void agg_gather(
    ushort* __restrict__ Agg, const ushort* __restrict__ Hc,
    const int* __restrict__ acsr, const int* __restrict__ aoff,
    const int* __restrict__ cnt, int N)
{
    const int g = threadIdx.x >> 5, lane = threadIdx.x & 31;
    const int n = blockIdx.x * 8 + g;
    if (n >= N) return;
    const int sbase = n * RR;
    int idx = aoff[sbase];                 // node's edges contiguous from here
    const ushort* hbase = Hc + lane * 4;
    ushort* obase = Agg + (size_t)n * 1024 + lane * 4;

    for (int r = 0; r < RR; r++) {
        const int c = cnt[sbase + r];
        ushort4v outv = (ushort4v)0;
        if (c > 0) {
            float4 acc = {0.f, 0.f, 0.f, 0.f};
            int i = 0;
            for (; i + 4 <= c; i += 4) {
                int s0 = acsr[idx + i],     s1 = acsr[idx + i + 1];
                int s2 = acsr[idx + i + 2], s3 = acsr[idx + i + 3];
                ushort4 y0 = *(const ushort4*)(hbase + (size_t)s0 * 128);
                ushort4 y1 = *(const ushort4*)(hbase + (size_t)s1 * 128);
                ushort4 y2 = *(const ushort4*)(hbase + (size_t)s2 * 128);
                ushort4 y3 = *(const ushort4*)(hbase + (size_t)s3 * 128);
                acc.x += (b2f(y0.x) + b2f(y1.x)) + (b2f(y2.x) + b2f(y3.x));
                acc.y += (b2f(y0.y) + b2f(y1.y)) + (b2f(y2.y) + b2f(y3.y));
                acc.z += (b2f(y0.z) + b2f(y1.z)) + (b2f(y2.z) + b2f(y3.z));
                acc.w += (b2f(y0.w) + b2f(y1.w)) + (b2f(y2.w) + b2f(y3.w));
            }
            for (; i < c; i++) {
                int s0 = acsr[idx + i];
                ushort4 y0 = *(const ushort4*)(hbase + (size_t)s0 * 128);
                acc.x += b2f(y0.x); acc.y += b2f(y0.y);
                acc.z += b2f(y0.z); acc.w += b2f(y0.w);
            }
            const float inv = 1.f / (float)c;
            outv[0] = f2b(acc.x * inv); outv[1] = f2b(acc.y * inv);
            outv[2] = f2b(acc.z * inv); outv[3] = f2b(acc.w * inv);
            idx += c;
        }
        __builtin_nontemporal_store(outv, (ushort4v*)(obase + r * 128));
    }
}

// ---------------------------------------------------------------------------
// h_next = (1-tau)*h + tau*hn  (hn already relu'd by GEMM epilogue);
// writes fp32 hn and compact bf16 Hc
// ---------------------------------------------------------------------------
__global__ void finalize(const float* __restrict__ hp, float* __restrict__ hn,
                         const ushort* __restrict__ TAUb, ushort* __restrict__ Hc,
                         int total4)
{
    int idx = blockIdx.x * 256 + threadIdx.x;
    if (idx >= total4) return;
    const float4 p = ((const float4*)hp)[idx];
    const float4 a = ((const float4*)hn)[idx];
    const ushort4 t4 = ((const ushort4*)TAUb)[idx];
    float4 o;
    o.x = p.x + b2f(t4.x) * (a.x - p.x);
    o.y = p.y + b2f(t4.y) * (a.y - p.y);
    o.z = p.z + b2f(t4.z) * (a.z - p.z);
    o.w = p.w + b2f(t4.w) * (a.w - p.w);
    ((float4*)hn)[idx] = o;
    ushort4 ob = { f2b(o.x), f2b(o.y), f2b(o.z), f2b(o.w) };
    *(ushort4*)(Hc + (size_t)idx * 4) = ob;
}

// ---------------------------------------------------------------------------
extern "C" void kernel_launch(void* const* d_in, const int* in_sizes, int n_in,
                              void* d_out, int out_size, void* d_ws, size_t ws_size,
                              hipStream_t stream)
{
    const float* x      = (const float*)d_in[0];
    const int*   src    = (const int*)  d_in[1];
    const int*   dst    = (const int*)  d_in[2];
    const int*   etyp   = (const int*)  d_in[3];
    const float* projW  = (const float*)d_in[4];
    const float* projb  = (const float*)d_in[5];
    const float* basis1 = (const float*)d_in[6];
    const float* comp1  = (const float*)d_in[7];
    const float* root1  = (const float*)d_in[8];
    const float* bias1  = (const float*)d_in[9];
    const float* basis2 = (const float*)d_in[10];
    const float* comp2  = (const float*)d_in[11];
    const float* root2  = (const float*)d_in[12];
    const float* bias2  = (const float*)d_in[13];
    const float* outW   = (const float*)d_in[14];
    const float* outb   = (const float*)d_in[15];

    const int N    = in_sizes[0] / D;
    const int E    = in_sizes[1];
    const int OUTD = in_sizes[15];

    float* out  = (float*)d_out;
    float* lat0 = out + (size_t)N * OUTD;
    float* lat1 = lat0 + (size_t)N * D;
    float* lat2 = lat1 + (size_t)N * D;

    // ---- workspace layout ----
    char* p = (char*)d_ws;
    ushort* Agg   = (ushort*)p;  p += (size_t)N * 1024 * 2;   // [N][8*128] bf16
    ushort* Hc    = (ushort*)p;  p += (size_t)N * 128 * 2;    // [N][128] bf16 (compact h)
    ushort* TAUb  = (ushort*)p;  p += (size_t)N * D * 2;
    ushort* projWT = (ushort*)p; p += 16384 * 2;
    ushort* outWT  = (ushort*)p; p += 16384 * 2;
    ushort* bigBT1 = (ushort*)p; p += (size_t)128 * 1152 * 2;
    ushort* bigBT2 = (ushort*)p; p += (size_t)128 * 1152 * 2;
    int* cnt_i  = (int*)p;       p += (size_t)N * RR * 4;
    int* deg_i  = (int*)p;       p += (size_t)N * 4;
    int* acur   = (int*)p;       p += (size_t)N * RR * 4;
    int* gcur   = (int*)p;       p += (size_t)N * 4;
    int* aoff   = (int*)p;       p += (size_t)N * RR * 4;
    int* goff   = (int*)p;       p += (size_t)N * 4;
    int* acsr   = (int*)p;       p += (size_t)E * 4;
    int* gcsr   = (int*)p;       p += (size_t)E * 4;
    int* bsum   = (int*)p;       p += 4096;

    if ((size_t)(p - (char*)d_ws) > ws_size) return;  // fails loudly

    // zero only the counters that accumulate (cnt_i, deg_i contiguous)
    hipMemsetAsync(cnt_i, 0, sizeof(int) * ((size_t)N * RR + N), stream);

    // weight prep
    build_bigBT<<<(128 * 1152 + 255) / 256, 256, 0, stream>>>(basis1, comp1, root1, bigBT1);
    build_bigBT<<<(128 * 1152 + 255) / 256, 256, 0, stream>>>(basis2, comp2, root2, bigBT2);
    transpose_pad<<<64, 256, 0, stream>>>(projW, projWT, 128);
    transpose_pad<<<64, 256, 0, stream>>>(outW, outWT, OUTD);

    cast_x<<<(N * 32 + 255) / 256, 256, 0, stream>>>(x, Hc, N * 32);

    count_edges<<<(E / 4 + 255) / 256, 256, 0, stream>>>(src, dst, etyp, cnt_i, deg_i, E);

    {   // exclusive scans -> CSR offsets
        int n1 = N * RR, nb1 = (n1 + 1023) / 1024;
        scan1<<<nb1, 256, 0, stream>>>(cnt_i, bsum, n1);
        scan_top<<<1, 1024, 0, stream>>>(bsum, nb1);
        scan2<<<nb1, 256, 0, stream>>>(cnt_i, bsum, aoff, n1);
        int nb2 = (N + 1023) / 1024;
        scan1<<<nb2, 256, 0, stream>>>(deg_i, bsum, N);
        scan_top<<<1, 1024, 0, stream>>>(bsum, nb2);
        scan2<<<nb2, 256, 0, stream>>>(deg_i, bsum, goff, N);
    }

    copy_off<<<(N * RR + 255) / 256, 256, 0, stream>>>(aoff, acur, N * RR, goff, gcur, N);

    fill_both<<<(E / 4 + 255) / 256, 256, 0, stream>>>(
        src, dst, etyp, acur, acsr, gcur, gcsr, E);

    const int mb = (N + 127) / 128;
    const int nodeblocks = (N + 7) / 8;

    // proj: lat0 = relu(x @ projW + projb); bf16 -> Hc (in-place safe)
    gemm_bf16<true, true, true, true><<<mb, 256, 0, stream>>>(
        Hc, 128, 2, Hc, 128, projWT, 1, projb, lat0, 128, Hc, 128, N, 128);

    const ushort* bigBT[2] = {bigBT1, bigBT2};
    const float* biases[2] = {bias1, bias2};
    float* lats[3]         = {lat0, lat1, lat2};

    for (int l = 0; l < 2; l++) {
        float* hn = lats[l + 1];

        gate_gather<<<nodeblocks, 256, 0, stream>>>(Hc, gcsr, goff, deg_i, TAUb, N);
        agg_gather<<<nodeblocks, 256, 0, stream>>>(Agg, Hc, acsr, aoff, cnt_i, N);

        // hn = relu([Agg | Hc] @ [W_1..W_8; root] + bias)
        gemm_bf16<true, true, true, false><<<mb, 256, 0, stream>>>(
            Agg, 1024, 16, Hc, 128, bigBT[l], 9, biases[l], hn, 128, nullptr, 0, N, 128);

        finalize<<<(N * 32 + 255) / 256, 256, 0, stream>>>(
            lats[l], hn, TAUb, Hc, N * 32);
    }

    // out = lat2 @ outW + outb
    gemm_bf16<true, false, true, false><<<mb, 256, 0, stream>>>(
        Hc, 128, 2, Hc, 128, outWT, 1, outb, out, OUTD, nullptr, 0, N, OUTD);
}

// Round 4
// 1179.562 us; speedup vs baseline: 1.1012x; 1.1012x over previous
//
#include <hip/hip_runtime.h>
#include <cstdint>
#include <cstddef>

#define D 128
#define RR 8

typedef __attribute__((ext_vector_type(8))) short short8;
typedef __attribute__((ext_vector_type(4))) float f32x4;
typedef __attribute__((ext_vector_type(4))) unsigned short ushort4v;

__device__ inline ushort f2b(float x) {
    union { float f; unsigned u; } v; v.f = x;
    unsigned r = v.u + 0x7fff + ((v.u >> 16) & 1);
    return (ushort)(r >> 16);
}
__device__ inline float b2f(ushort u) {
    union { unsigned u; float f; } v; v.u = ((unsigned)u) << 16; return v.f;
}

// async global->LDS, 16B per lane; LDS dest = wave-uniform base + lane*16
__device__ inline void gload_lds16(const ushort* g, ushort* l) {
    __builtin_amdgcn_global_load_lds(
        (const __attribute__((address_space(1))) unsigned int*)g,
        (__attribute__((address_space(3))) unsigned int*)l, 16, 0, 0);
}

// ---------------------------------------------------------------------------
// bf16 MFMA GEMM with SPLIT A: C[M, ncol] = [A0 | A1] @ B (+bias) (+relu)
// K-steps 0..k0steps-1 read A0 (lda0), steps k0steps.. read A1 (lda1).
// BT: [128][ktiles*128] bf16, row = out col.  256 thr = 4 waves; tile 128x128;
// BK=64 (32 KB LDS -> 4 blocks/CU).  global_load_lds width=16, LDS linear,
// XOR bank swizzle applied on per-lane GLOBAL source addr + ds_read addr.
// OOB tail rows clamp to row M-1 (valid memory; never stored).
// In-place A==Cb safe (block only reads/writes its own rows).
// ---------------------------------------------------------------------------
template<bool BIAS, bool RELU, bool STF, bool STB>
__global__ __launch_bounds__(256, 4) void gemm_bf16(
    const ushort* __restrict__ A0, int lda0, int k0steps,
    const ushort* __restrict__ A1, int lda1,
    const ushort* __restrict__ BT, int ktiles,
    const float* __restrict__ bias, float* __restrict__ Cf, int ldcf,
    ushort* __restrict__ Cb, int ldcb, int M, int ncol)
{
    __shared__ ushort As[128 * 64];
    __shared__ ushort Bs[128 * 64];
    const int tid = threadIdx.x;
    const int m0 = blockIdx.x * 128;
    const int ldb = ktiles * 128;
    const int ksteps = ktiles * 2;          // BK = 64

    const int w = tid >> 6, lane = tid & 63;
    const int wm = (w & 1) * 64, wn = (w >> 1) * 64;
    const int l15 = lane & 15, quad = lane >> 4;

    // staging geometry: per (wave, it) the wave fills LDS groups
    // gi = w*256 + it*64 + lane ; row = gi>>3, g = gi&7 (8 x 16B groups/row).
    // Data at linear LDS group (row,g) comes from global col-group g^(row&7).
    const ushort* a0p[4];
    const ushort* a1p[4];
    const ushort* bp[4];
#pragma unroll
    for (int it = 0; it < 4; it++) {
        int gi = w * 256 + it * 64 + lane;
        int row = gi >> 3, g = gi & 7;
        int cg = g ^ (row & 7);
        int gr = m0 + row; if (gr > M - 1) gr = M - 1;   // clamp tail
        a0p[it] = A0 + (size_t)gr * lda0 + (cg << 3);
        a1p[it] = A1 + (size_t)gr * lda1 + (cg << 3);
        bp[it]  = BT + (size_t)row * ldb + (cg << 3);    // B rows 0..127 always valid
    }

    f32x4 acc[4][4];
    const f32x4 z4 = {0.f, 0.f, 0.f, 0.f};
#pragma unroll
    for (int i = 0; i < 4; i++)
#pragma unroll
        for (int j = 0; j < 4; j++) acc[i][j] = z4;

    for (int kt = 0; kt < ksteps; kt++) {
        const int ko = kt * 64;
        if (kt < k0steps) {
#pragma unroll
            for (int it = 0; it < 4; it++)
                gload_lds16(a0p[it] + ko, As + w * 2048 + it * 512);
        } else {
            const int ko1 = (kt - k0steps) * 64;
#pragma unroll
            for (int it = 0; it < 4; it++)
                gload_lds16(a1p[it] + ko1, As + w * 2048 + it * 512);
        }
#pragma unroll
        for (int it = 0; it < 4; it++)
            gload_lds16(bp[it] + ko, Bs + w * 2048 + it * 512);
        __syncthreads();   // compiler emits vmcnt(0) drain before barrier

#pragma unroll
        for (int ks = 0; ks < 64; ks += 32) {
            const int q0 = (ks >> 3) + quad;        // k-group 0..7
            short8 af[4], bfr[4];
#pragma unroll
            for (int i = 0; i < 4; i++) {
                int row = wm + i * 16 + l15;
                af[i] = *(const short8*)(&As[row * 64 + ((q0 ^ (row & 7)) << 3)]);
            }
#pragma unroll
            for (int j = 0; j < 4; j++) {
                int row = wn + j * 16 + l15;
                bfr[j] = *(const short8*)(&Bs[row * 64 + ((q0 ^ (row & 7)) << 3)]);
            }
#pragma unroll
            for (int i = 0; i < 4; i++)
#pragma unroll
                for (int j = 0; j < 4; j++)
                    acc[i][j] = __builtin_amdgcn_mfma_f32_16x16x32_bf16(
                        af[i], bfr[j], acc[i][j], 0, 0, 0);
        }
        __syncthreads();
    }

    // epilogue: C[m=quad*4+q][n=l15] per 16x16 frag
#pragma unroll
    for (int i = 0; i < 4; i++) {
#pragma unroll
        for (int q = 0; q < 4; q++) {
            int gm = m0 + wm + i * 16 + quad * 4 + q;
            if (gm >= M) continue;
#pragma unroll
            for (int j = 0; j < 4; j++) {
                int gn = wn + j * 16 + l15;
                if (gn >= ncol) continue;
                float v = acc[i][j][q];
                if (BIAS) v += bias[gn];
                if (RELU) v = v > 0.f ? v : 0.f;
                if (STF) Cf[(size_t)gm * ldcf + gn] = v;
                if (STB) Cb[(size_t)gm * ldcb + gn] = f2b(v);
            }
        }
    }
}

// ---------------------------------------------------------------------------
// bigBT[f][c]: c<1024 -> W_{c>>7}[c&127][f];  c>=1024 -> root[c-1024][f]
// ---------------------------------------------------------------------------
__global__ void build_bigBT(const float* __restrict__ basis,
                            const float* __restrict__ comp,
                            const float* __restrict__ root,
                            ushort* __restrict__ BT)
{
    int i = blockIdx.x * 256 + threadIdx.x;
    if (i >= 128 * 1152) return;
    int f = i / 1152, c = i - f * 1152;
    float a;
    if (c < 1024) {
        int r = c >> 7, d = c & 127;
        a = 0.f;
#pragma unroll
        for (int b = 0; b < 4; b++)
            a += comp[r * 4 + b] * basis[(b * 128 + d) * 128 + f];
    } else {
        a = root[(c - 1024) * 128 + f];
    }
    BT[i] = f2b(a);
}

// out[f*128+k] = bf16(in[k*cols+f]) for f<cols else 0   (in: [128][cols])
__global__ void transpose_pad(const float* __restrict__ in, ushort* __restrict__ out,
                              int cols)
{
    int i = blockIdx.x * 256 + threadIdx.x;
    if (i >= 128 * 128) return;
    int k = i & 127, f = i >> 7;
    out[i] = (f < cols) ? f2b(in[k * cols + f]) : (ushort)0;
}

// x [N][128] fp32 -> compact bf16 Hc [N][128]
__global__ void cast_x(const float* __restrict__ in, ushort* __restrict__ Hc, int total4)
{
    int i = blockIdx.x * 256 + threadIdx.x;
    if (i >= total4) return;
    float4 v = ((const float4*)in)[i];
    ushort4 o = { f2b(v.x), f2b(v.y), f2b(v.z), f2b(v.w) };
    *(ushort4*)(Hc + (size_t)i * 4) = o;
}

// ---------------------------------------------------------------------------
// round-2 form (measured good): scalar per-edge loop; independent loads give
// the atomic chain memory-level parallelism.
// ---------------------------------------------------------------------------
__global__ void count_edges(const int* __restrict__ src, const int* __restrict__ dst,
                            const int* __restrict__ et, int* __restrict__ cnt,
                            int* __restrict__ deg, int E)
{
    int e0 = (blockIdx.x * 256 + threadIdx.x) * 4;
#pragma unroll
    for (int j = 0; j < 4; j++) {
        int e = e0 + j;
        if (e < E) {
            atomicAdd(&cnt[dst[e] * RR + et[e]], 1);
            atomicAdd(&deg[src[e]], 1);
        }
    }
}

// ---------------------------------------------------------------------------
// 3-phase exclusive scan (1024 elements per block)
// ---------------------------------------------------------------------------
__global__ void scan1(const int* __restrict__ in, int* __restrict__ bsum, int n)
{
    __shared__ int s[256];
    const int b = blockIdx.x, t = threadIdx.x;
    const int base = b * 1024;
    int v = 0;
#pragma unroll
    for (int i = 0; i < 4; i++) {
        int idx = base + t * 4 + i;
        if (idx < n) v += in[idx];
    }
    s[t] = v; __syncthreads();
    for (int off = 128; off > 0; off >>= 1) {
        if (t < off) s[t] += s[t + off];
        __syncthreads();
    }
    if (t == 0) bsum[b] = s[0];
}

__global__ void scan_top(int* __restrict__ bsum, int nb)
{
    __shared__ int s[1024];
    const int t = threadIdx.x;
    int v = (t < nb) ? bsum[t] : 0;
    s[t] = v; __syncthreads();
    for (int off = 1; off < 1024; off <<= 1) {
        int x = (t >= off) ? s[t - off] : 0;
        __syncthreads();
        s[t] += x;
        __syncthreads();
    }
    if (t < nb) bsum[t] = s[t] - v;   // exclusive
}

__global__ void scan2(const int* __restrict__ in, const int* __restrict__ bsum,
                      int* __restrict__ out, int n)
{
    __shared__ int s[256];
    const int b = blockIdx.x, t = threadIdx.x;
    const int base = b * 1024;
    int loc[4];
    int v = 0;
#pragma unroll
    for (int i = 0; i < 4; i++) {
        int idx = base + t * 4 + i;
        int x = (idx < n) ? in[idx] : 0;
        loc[i] = v; v += x;
    }
    s[t] = v; __syncthreads();
    for (int off = 1; off < 256; off <<= 1) {
        int x = (t >= off) ? s[t - off] : 0;
        __syncthreads();
        s[t] += x;
        __syncthreads();
    }
    const int add = bsum[b] + (s[t] - v);
#pragma unroll
    for (int i = 0; i < 4; i++) {
        int idx = base + t * 4 + i;
        if (idx < n) out[idx] = add + loc[i];
    }
}

// ---------------------------------------------------------------------------
// both CSR fills in one pass — round-2 form (independent aoff/goff reads feed
// the atomic chain MLP; measured 170 µs vs 289 for seeded-cursor variant).
// Round-4 delta: non-temporal scatter stores (don't let the 12.8 MB random
// store stream evict hot aoff/acur lines from L2).
// ---------------------------------------------------------------------------
__global__ void fill_both(const int* __restrict__ src, const int* __restrict__ dst,
                          const int* __restrict__ et,
                          const int* __restrict__ aoff, int* __restrict__ acur,
                          int* __restrict__ acsr,
                          const int* __restrict__ goff, int* __restrict__ gcur,
                          int* __restrict__ gcsr, int E)
{
    int e0 = (blockIdx.x * 256 + threadIdx.x) * 4;
#pragma unroll
    for (int j = 0; j < 4; j++) {
        int e = e0 + j;
        if (e < E) {
            int s0 = src[e], d0 = dst[e];
            int seg = d0 * RR + et[e];
            int p = aoff[seg] + atomicAdd(&acur[seg], 1);
            __builtin_nontemporal_store(s0, &acsr[p]);
            int pg = goff[s0] + atomicAdd(&gcur[s0], 1);
            __builtin_nontemporal_store(d0, &gcsr[pg]);
        }
    }
}

// ---------------------------------------------------------------------------
// gate gather (compact bf16 Hc): TAUb[n] = bf16(tanh( mean_out (h[n]-h[dst])^2 ))
// 4-unrolled head + PAIRWISE remainder (deg avg 16; keep >=2 loads in flight).
// ---------------------------------------------------------------------------
__global__ __launch_bounds__(256) void gate_gather(
    const ushort* __restrict__ Hc, const int* __restrict__ gcsr,
    const int* __restrict__ goff, const int* __restrict__ deg,
    ushort* __restrict__ TAUb, int N)
{
    const int g = threadIdx.x >> 5, lane = threadIdx.x & 31;
    const int n = blockIdx.x * 8 + g;
    if (n >= N) return;
    const int start = goff[n];
    const int c = deg[n];
    const ushort* hbase = Hc + lane * 4;
    ushort4 a4 = *(const ushort4*)(hbase + (size_t)n * 128);
    float ax = b2f(a4.x), ay = b2f(a4.y), az = b2f(a4.z), aw = b2f(a4.w);
    float4 acc = {0.f, 0.f, 0.f, 0.f};
    int i = 0;
    for (; i + 4 <= c; i += 4) {
        int d0 = gcsr[start + i],     d1 = gcsr[start + i + 1];
        int d2 = gcsr[start + i + 2], d3 = gcsr[start + i + 3];
        ushort4 b0 = *(const ushort4*)(hbase + (size_t)d0 * 128);
        ushort4 b1 = *(const ushort4*)(hbase + (size_t)d1 * 128);
        ushort4 b2 = *(const ushort4*)(hbase + (size_t)d2 * 128);
        ushort4 b3 = *(const ushort4*)(hbase + (size_t)d3 * 128);
        float dx, dy, dz, dw;
        dx = ax - b2f(b0.x); dy = ay - b2f(b0.y); dz = az - b2f(b0.z); dw = aw - b2f(b0.w);
        acc.x += dx * dx; acc.y += dy * dy; acc.z += dz * dz; acc.w += dw * dw;
        dx = ax - b2f(b1.x); dy = ay - b2f(b1.y); dz = az - b2f(b1.z); dw = aw - b2f(b1.w);
        acc.x += dx * dx; acc.y += dy * dy; acc.z += dz * dz; acc.w += dw * dw;
        dx = ax - b2f(b2.x); dy = ay - b2f(b2.y); dz = az - b2f(b2.z); dw = aw - b2f(b2.w);
        acc.x += dx * dx; acc.y += dy * dy; acc.z += dz * dz; acc.w += dw * dw;
        dx = ax - b2f(b3.x); dy = ay - b2f(b3.y); dz = az - b2f(b3.z); dw = aw - b2f(b3.w);
        acc.x += dx * dx; acc.y += dy * dy; acc.z += dz * dz; acc.w += dw * dw;
    }
    if (i + 2 <= c) {
        int d0 = gcsr[start + i], d1 = gcsr[start + i + 1];
        ushort4 b0 = *(const ushort4*)(hbase + (size_t)d0 * 128);
        ushort4 b1 = *(const ushort4*)(hbase + (size_t)d1 * 128);
        float dx, dy, dz, dw;
        dx = ax - b2f(b0.x); dy = ay - b2f(b0.y); dz = az - b2f(b0.z); dw = aw - b2f(b0.w);
        acc.x += dx * dx; acc.y += dy * dy; acc.z += dz * dz; acc.w += dw * dw;
        dx = ax - b2f(b1.x); dy = ay - b2f(b1.y); dz = az - b2f(b1.z); dw = aw - b2f(b1.w);
        acc.x += dx * dx; acc.y += dy * dy; acc.z += dz * dz; acc.w += dw * dw;
        i += 2;
    }
    if (i < c) {
        int d0 = gcsr[start + i];
        ushort4 b0 = *(const ushort4*)(hbase + (size_t)d0 * 128);
        float dx = ax - b2f(b0.x), dy = ay - b2f(b0.y),
              dz = az - b2f(b0.z), dw = aw - b2f(b0.w);
        acc.x += dx * dx; acc.y += dy * dy; acc.z += dz * dz; acc.w += dw * dw;
    }
    const float inv = (c > 0) ? (1.f / (float)c) : 1.f;
    ushort4 t;
    t.x = f2b(tanhf(acc.x * inv)); t.y = f2b(tanhf(acc.y * inv));
    t.z = f2b(tanhf(acc.z * inv)); t.w = f2b(tanhf(acc.w * inv));
    *(ushort4*)(TAUb + (size_t)n * D + lane * 4) = t;
}

// ---------------------------------------------------------------------------
// agg gather, NODE-per-group: one 32-lane group walks all 8 relation segments
// of node n (contiguous in acsr).  4-unroll head + PAIRWISE remainder (seg
// counts avg ~2, so the pair path is the hot one).  NT output stores.
// ---------------------------------------------------------------------------
__global__ __launch_bounds__(256) void agg_gather(
    ushort* __restrict__ Agg, const ushort* __restrict__ Hc,
    const int* __restrict__ acsr, const int* __restrict__ aoff,
    const int* __restrict__ cnt, int N)
{
    const int g = threadIdx.x >> 5, lane = threadIdx.x & 31;
    const int n = blockIdx.x * 8 + g;
    if (n >= N) return;
    const int sbase = n * RR;
    int idx = aoff[sbase];                 // node's edges contiguous from here
    const ushort* hbase = Hc + lane * 4;
    ushort* obase = Agg + (size_t)n * 1024 + lane * 4;

    for (int r = 0; r < RR; r++) {
        const int c = cnt[sbase + r];
        ushort4v outv = (ushort4v)0;
        if (c > 0) {
            float4 acc = {0.f, 0.f, 0.f, 0.f};
            int i = 0;
            for (; i + 4 <= c; i += 4) {
                int s0 = acsr[idx + i],     s1 = acsr[idx + i + 1];
                int s2 = acsr[idx + i + 2], s3 = acsr[idx + i + 3];
                ushort4 y0 = *(const ushort4*)(hbase + (size_t)s0 * 128);
                ushort4 y1 = *(const ushort4*)(hbase + (size_t)s1 * 128);
                ushort4 y2 = *(const ushort4*)(hbase + (size_t)s2 * 128);
                ushort4 y3 = *(const ushort4*)(hbase + (size_t)s3 * 128);
                acc.x += (b2f(y0.x) + b2f(y1.x)) + (b2f(y2.x) + b2f(y3.x));
                acc.y += (b2f(y0.y) + b2f(y1.y)) + (b2f(y2.y) + b2f(y3.y));
                acc.z += (b2f(y0.z) + b2f(y1.z)) + (b2f(y2.z) + b2f(y3.z));
                acc.w += (b2f(y0.w) + b2f(y1.w)) + (b2f(y2.w) + b2f(y3.w));
            }
            if (i + 2 <= c) {
                int s0 = acsr[idx + i], s1 = acsr[idx + i + 1];
                ushort4 y0 = *(const ushort4*)(hbase + (size_t)s0 * 128);
                ushort4 y1 = *(const ushort4*)(hbase + (size_t)s1 * 128);
                acc.x += b2f(y0.x) + b2f(y1.x); acc.y += b2f(y0.y) + b2f(y1.y);
                acc.z += b2f(y0.z) + b2f(y1.z); acc.w += b2f(y0.w) + b2f(y1.w);
                i += 2;
            }
            if (i < c) {
                int s0 = acsr[idx + i];
                ushort4 y0 = *(const ushort4*)(hbase + (size_t)s0 * 128);
                acc.x += b2f(y0.x); acc.y += b2f(y0.y);
                acc.z += b2f(y0.z); acc.w += b2f(y0.w);
            }
            const float inv = 1.f / (float)c;
            outv[0] = f2b(acc.x * inv); outv[1] = f2b(acc.y * inv);
            outv[2] = f2b(acc.z * inv); outv[3] = f2b(acc.w * inv);
            idx += c;
        }
        __builtin_nontemporal_store(outv, (ushort4v*)(obase + r * 128));
    }
}

// ---------------------------------------------------------------------------
// h_next = (1-tau)*h + tau*hn  (hn already relu'd by GEMM epilogue);
// writes fp32 hn and compact bf16 Hc
// ---------------------------------------------------------------------------
__global__ void finalize(const float* __restrict__ hp, float* __restrict__ hn,
                         const ushort* __restrict__ TAUb, ushort* __restrict__ Hc,
                         int total4)
{
    int idx = blockIdx.x * 256 + threadIdx.x;
    if (idx >= total4) return;
    const float4 p = ((const float4*)hp)[idx];
    const float4 a = ((const float4*)hn)[idx];
    const ushort4 t4 = ((const ushort4*)TAUb)[idx];
    float4 o;
    o.x = p.x + b2f(t4.x) * (a.x - p.x);
    o.y = p.y + b2f(t4.y) * (a.y - p.y);
    o.z = p.z + b2f(t4.z) * (a.z - p.z);
    o.w = p.w + b2f(t4.w) * (a.w - p.w);
    ((float4*)hn)[idx] = o;
    ushort4 ob = { f2b(o.x), f2b(o.y), f2b(o.z), f2b(o.w) };
    *(ushort4*)(Hc + (size_t)idx * 4) = ob;
}

// ---------------------------------------------------------------------------
extern "C" void kernel_launch(void* const* d_in, const int* in_sizes, int n_in,
                              void* d_out, int out_size, void* d_ws, size_t ws_size,
                              hipStream_t stream)
{
    const float* x      = (const float*)d_in[0];
    const int*   src    = (const int*)  d_in[1];
    const int*   dst    = (const int*)  d_in[2];
    const int*   etyp   = (const int*)  d_in[3];
    const float* projW  = (const float*)d_in[4];
    const float* projb  = (const float*)d_in[5];
    const float* basis1 = (const float*)d_in[6];
    const float* comp1  = (const float*)d_in[7];
    const float* root1  = (const float*)d_in[8];
    const float* bias1  = (const float*)d_in[9];
    const float* basis2 = (const float*)d_in[10];
    const float* comp2  = (const float*)d_in[11];
    const float* root2  = (const float*)d_in[12];
    const float* bias2  = (const float*)d_in[13];
    const float* outW   = (const float*)d_in[14];
    const float* outb   = (const float*)d_in[15];

    const int N    = in_sizes[0] / D;
    const int E    = in_sizes[1];
    const int OUTD = in_sizes[15];

    float* out  = (float*)d_out;
    float* lat0 = out + (size_t)N * OUTD;
    float* lat1 = lat0 + (size_t)N * D;
    float* lat2 = lat1 + (size_t)N * D;

    // ---- workspace layout ----
    char* p = (char*)d_ws;
    ushort* Agg   = (ushort*)p;  p += (size_t)N * 1024 * 2;   // [N][8*128] bf16
    ushort* Hc    = (ushort*)p;  p += (size_t)N * 128 * 2;    // [N][128] bf16 (compact h)
    ushort* TAUb  = (ushort*)p;  p += (size_t)N * D * 2;
    ushort* projWT = (ushort*)p; p += 16384 * 2;
    ushort* outWT  = (ushort*)p; p += 16384 * 2;
    ushort* bigBT1 = (ushort*)p; p += (size_t)128 * 1152 * 2;
    ushort* bigBT2 = (ushort*)p; p += (size_t)128 * 1152 * 2;
    int* cnt_i  = (int*)p;       p += (size_t)N * RR * 4;
    int* deg_i  = (int*)p;       p += (size_t)N * 4;
    int* acur   = (int*)p;       p += (size_t)N * RR * 4;
    int* gcur   = (int*)p;       p += (size_t)N * 4;
    int* aoff   = (int*)p;       p += (size_t)N * RR * 4;
    int* goff   = (int*)p;       p += (size_t)N * 4;
    int* acsr   = (int*)p;       p += (size_t)E * 4;
    int* gcsr   = (int*)p;       p += (size_t)E * 4;
    int* bsum   = (int*)p;       p += 4096;

    if ((size_t)(p - (char*)d_ws) > ws_size) return;  // fails loudly

    // zero counters (cnt_i, deg_i, acur, gcur contiguous)
    hipMemsetAsync(cnt_i, 0, sizeof(int) * 2 * ((size_t)N * RR + N), stream);

    // weight prep
    build_bigBT<<<(128 * 1152 + 255) / 256, 256, 0, stream>>>(basis1, comp1, root1, bigBT1);
    build_bigBT<<<(128 * 1152 + 255) / 256, 256, 0, stream>>>(basis2, comp2, root2, bigBT2);
    transpose_pad<<<64, 256, 0, stream>>>(projW, projWT, 128);
    transpose_pad<<<64, 256, 0, stream>>>(outW, outWT, OUTD);

    cast_x<<<(N * 32 + 255) / 256, 256, 0, stream>>>(x, Hc, N * 32);

    count_edges<<<(E / 4 + 255) / 256, 256, 0, stream>>>(src, dst, etyp, cnt_i, deg_i, E);

    {   // exclusive scans -> CSR offsets
        int n1 = N * RR, nb1 = (n1 + 1023) / 1024;
        scan1<<<nb1, 256, 0, stream>>>(cnt_i, bsum, n1);
        scan_top<<<1, 1024, 0, stream>>>(bsum, nb1);
        scan2<<<nb1, 256, 0, stream>>>(cnt_i, bsum, aoff, n1);
        int nb2 = (N + 1023) / 1024;
        scan1<<<nb2, 256, 0, stream>>>(deg_i, bsum, N);
        scan_top<<<1, 1024, 0, stream>>>(bsum, nb2);
        scan2<<<nb2, 256, 0, stream>>>(deg_i, bsum, goff, N);
    }

    fill_both<<<(E / 4 + 255) / 256, 256, 0, stream>>>(
        src, dst, etyp, aoff, acur, acsr, goff, gcur, gcsr, E);

    const int mb = (N + 127) / 128;
    const int nodeblocks = (N + 7) / 8;

    // proj: lat0 = relu(x @ projW + projb); bf16 -> Hc (in-place safe)
    gemm_bf16<true, true, true, true><<<mb, 256, 0, stream>>>(
        Hc, 128, 2, Hc, 128, projWT, 1, projb, lat0, 128, Hc, 128, N, 128);

    const ushort* bigBT[2] = {bigBT1, bigBT2};
    const float* biases[2] = {bias1, bias2};
    float* lats[3]         = {lat0, lat1, lat2};

    for (int l = 0; l < 2; l++) {
        float* hn = lats[l + 1];

        gate_gather<<<nodeblocks, 256, 0, stream>>>(Hc, gcsr, goff, deg_i, TAUb, N);
        agg_gather<<<nodeblocks, 256, 0, stream>>>(Agg, Hc, acsr, aoff, cnt_i, N);

        // hn = relu([Agg | Hc] @ [W_1..W_8; root] + bias)
        gemm_bf16<true, true, true, false><<<mb, 256, 0, stream>>>(
            Agg, 1024, 16, Hc, 128, bigBT[l], 9, biases[l], hn, 128, nullptr, 0, N, 128);

        finalize<<<(N * 32 + 255) / 256, 256, 0, stream>>>(
            lats[l], hn, TAUb, Hc, N * 32);
    }

    // out = lat2 @ outW + outb
    gemm_bf16<true, false, true, false><<<mb, 256, 0, stream>>>(
        Hc, 128, 2, Hc, 128, outWT, 1, outb, out, OUTD, nullptr, 0, N, OUTD);
}

// Round 5
// 1119.779 us; speedup vs baseline: 1.1600x; 1.0534x over previous
//
#include <hip/hip_runtime.h>
#include <cstdint>
#include <cstddef>

#define D 128
#define RR 8

typedef __attribute__((ext_vector_type(8))) short short8;
typedef __attribute__((ext_vector_type(4))) float f32x4;

__device__ inline ushort f2b(float x) {
    union { float f; unsigned u; } v; v.f = x;
    unsigned r = v.u + 0x7fff + ((v.u >> 16) & 1);
    return (ushort)(r >> 16);
}
__device__ inline float b2f(ushort u) {
    union { unsigned u; float f; } v; v.u = ((unsigned)u) << 16; return v.f;
}

// async global->LDS, 16B per lane; LDS dest = wave-uniform base + lane*16
__device__ inline void gload_lds16(const ushort* g, ushort* l) {
    __builtin_amdgcn_global_load_lds(
        (const __attribute__((address_space(1))) unsigned int*)g,
        (__attribute__((address_space(3))) unsigned int*)l, 16, 0, 0);
}

// ---------------------------------------------------------------------------
// bf16 MFMA GEMM with SPLIT A: C[M, ncol] = [A0 | A1] @ B (+bias) (+relu)
// K-steps 0..k0steps-1 read A0 (lda0), steps k0steps.. read A1 (lda1).
// BT: [128][ktiles*128] bf16, row = out col.  256 thr = 4 waves; tile 128x128;
// BK=64 (32 KB LDS -> 4 blocks/CU).  global_load_lds width=16, LDS linear,
// XOR bank swizzle applied on per-lane GLOBAL source addr + ds_read addr.
// OOB tail rows clamp to row M-1 (valid memory; never stored).
// In-place A==Cb safe (block only reads/writes its own rows).
// ---------------------------------------------------------------------------
template<bool BIAS, bool RELU, bool STF, bool STB>
__global__ __launch_bounds__(256, 4) void gemm_bf16(
    const ushort* __restrict__ A0, int lda0, int k0steps,
    const ushort* __restrict__ A1, int lda1,
    const ushort* __restrict__ BT, int ktiles,
    const float* __restrict__ bias, float* __restrict__ Cf, int ldcf,
    ushort* __restrict__ Cb, int ldcb, int M, int ncol)
{
    __shared__ ushort As[128 * 64];
    __shared__ ushort Bs[128 * 64];
    const int tid = threadIdx.x;
    const int m0 = blockIdx.x * 128;
    const int ldb = ktiles * 128;
    const int ksteps = ktiles * 2;          // BK = 64

    const int w = tid >> 6, lane = tid & 63;
    const int wm = (w & 1) * 64, wn = (w >> 1) * 64;
    const int l15 = lane & 15, quad = lane >> 4;

    // staging geometry: per (wave, it) the wave fills LDS groups
    // gi = w*256 + it*64 + lane ; row = gi>>3, g = gi&7 (8 x 16B groups/row).
    // Data at linear LDS group (row,g) comes from global col-group g^(row&7).
    const ushort* a0p[4];
    const ushort* a1p[4];
    const ushort* bp[4];
#pragma unroll
    for (int it = 0; it < 4; it++) {
        int gi = w * 256 + it * 64 + lane;
        int row = gi >> 3, g = gi & 7;
        int cg = g ^ (row & 7);
        int gr = m0 + row; if (gr > M - 1) gr = M - 1;   // clamp tail
        a0p[it] = A0 + (size_t)gr * lda0 + (cg << 3);
        a1p[it] = A1 + (size_t)gr * lda1 + (cg << 3);
        bp[it]  = BT + (size_t)row * ldb + (cg << 3);    // B rows 0..127 always valid
    }

    f32x4 acc[4][4];
    const f32x4 z4 = {0.f, 0.f, 0.f, 0.f};
#pragma unroll
    for (int i = 0; i < 4; i++)
#pragma unroll
        for (int j = 0; j < 4; j++) acc[i][j] = z4;

    for (int kt = 0; kt < ksteps; kt++) {
        const int ko = kt * 64;
        if (kt < k0steps) {
#pragma unroll
            for (int it = 0; it < 4; it++)
                gload_lds16(a0p[it] + ko, As + w * 2048 + it * 512);
        } else {
            const int ko1 = (kt - k0steps) * 64;
#pragma unroll
            for (int it = 0; it < 4; it++)
                gload_lds16(a1p[it] + ko1, As + w * 2048 + it * 512);
        }
#pragma unroll
        for (int it = 0; it < 4; it++)
            gload_lds16(bp[it] + ko, Bs + w * 2048 + it * 512);
        __syncthreads();   // compiler emits vmcnt(0) drain before barrier

#pragma unroll
        for (int ks = 0; ks < 64; ks += 32) {
            const int q0 = (ks >> 3) + quad;        // k-group 0..7
            short8 af[4], bfr[4];
#pragma unroll
            for (int i = 0; i < 4; i++) {
                int row = wm + i * 16 + l15;
                af[i] = *(const short8*)(&As[row * 64 + ((q0 ^ (row & 7)) << 3)]);
            }
#pragma unroll
            for (int j = 0; j < 4; j++) {
                int row = wn + j * 16 + l15;
                bfr[j] = *(const short8*)(&Bs[row * 64 + ((q0 ^ (row & 7)) << 3)]);
            }
#pragma unroll
            for (int i = 0; i < 4; i++)
#pragma unroll
                for (int j = 0; j < 4; j++)
                    acc[i][j] = __builtin_amdgcn_mfma_f32_16x16x32_bf16(
                        af[i], bfr[j], acc[i][j], 0, 0, 0);
        }
        __syncthreads();
    }

    // epilogue: C[m=quad*4+q][n=l15] per 16x16 frag
#pragma unroll
    for (int i = 0; i < 4; i++) {
#pragma unroll
        for (int q = 0; q < 4; q++) {
            int gm = m0 + wm + i * 16 + quad * 4 + q;
            if (gm >= M) continue;
#pragma unroll
            for (int j = 0; j < 4; j++) {
                int gn = wn + j * 16 + l15;
                if (gn >= ncol) continue;
                float v = acc[i][j][q];
                if (BIAS) v += bias[gn];
                if (RELU) v = v > 0.f ? v : 0.f;
                if (STF) Cf[(size_t)gm * ldcf + gn] = v;
                if (STB) Cb[(size_t)gm * ldcb + gn] = f2b(v);
            }
        }
    }
}

// ---------------------------------------------------------------------------
// bigBT[f][c]: c<1024 -> W_{c>>7}[c&127][f];  c>=1024 -> root[c-1024][f]
// ---------------------------------------------------------------------------
__global__ void build_bigBT(const float* __restrict__ basis,
                            const float* __restrict__ comp,
                            const float* __restrict__ root,
                            ushort* __restrict__ BT)
{
    int i = blockIdx.x * 256 + threadIdx.x;
    if (i >= 128 * 1152) return;
    int f = i / 1152, c = i - f * 1152;
    float a;
    if (c < 1024) {
        int r = c >> 7, d = c & 127;
        a = 0.f;
#pragma unroll
        for (int b = 0; b < 4; b++)
            a += comp[r * 4 + b] * basis[(b * 128 + d) * 128 + f];
    } else {
        a = root[(c - 1024) * 128 + f];
    }
    BT[i] = f2b(a);
}

// out[f*128+k] = bf16(in[k*cols+f]) for f<cols else 0   (in: [128][cols])
__global__ void transpose_pad(const float* __restrict__ in, ushort* __restrict__ out,
                              int cols)
{
    int i = blockIdx.x * 256 + threadIdx.x;
    if (i >= 128 * 128) return;
    int k = i & 127, f = i >> 7;
    out[i] = (f < cols) ? f2b(in[k * cols + f]) : (ushort)0;
}

// x [N][128] fp32 -> compact bf16 Hc [N][128]
__global__ void cast_x(const float* __restrict__ in, ushort* __restrict__ Hc, int total4)
{
    int i = blockIdx.x * 256 + threadIdx.x;
    if (i >= total4) return;
    float4 v = ((const float4*)in)[i];
    ushort4 o = { f2b(v.x), f2b(v.y), f2b(v.z), f2b(v.w) };
    *(ushort4*)(Hc + (size_t)i * 4) = o;
}

// ---------------------------------------------------------------------------
// round-2 form (measured good): scalar per-edge loop; independent loads give
// the atomic chain memory-level parallelism.
// ---------------------------------------------------------------------------
__global__ void count_edges(const int* __restrict__ src, const int* __restrict__ dst,
                            const int* __restrict__ et, int* __restrict__ cnt,
                            int* __restrict__ deg, int E)
{
    int e0 = (blockIdx.x * 256 + threadIdx.x) * 4;
#pragma unroll
    for (int j = 0; j < 4; j++) {
        int e = e0 + j;
        if (e < E) {
            atomicAdd(&cnt[dst[e] * RR + et[e]], 1);
            atomicAdd(&deg[src[e]], 1);
        }
    }
}

// ---------------------------------------------------------------------------
// 3-phase exclusive scan (1024 elements per block)
// ---------------------------------------------------------------------------
__global__ void scan1(const int* __restrict__ in, int* __restrict__ bsum, int n)
{
    __shared__ int s[256];
    const int b = blockIdx.x, t = threadIdx.x;
    const int base = b * 1024;
    int v = 0;
#pragma unroll
    for (int i = 0; i < 4; i++) {
        int idx = base + t * 4 + i;
        if (idx < n) v += in[idx];
    }
    s[t] = v; __syncthreads();
    for (int off = 128; off > 0; off >>= 1) {
        if (t < off) s[t] += s[t + off];
        __syncthreads();
    }
    if (t == 0) bsum[b] = s[0];
}

__global__ void scan_top(int* __restrict__ bsum, int nb)
{
    __shared__ int s[1024];
    const int t = threadIdx.x;
    int v = (t < nb) ? bsum[t] : 0;
    s[t] = v; __syncthreads();
    for (int off = 1; off < 1024; off <<= 1) {
        int x = (t >= off) ? s[t - off] : 0;
        __syncthreads();
        s[t] += x;
        __syncthreads();
    }
    if (t < nb) bsum[t] = s[t] - v;   // exclusive
}

__global__ void scan2(const int* __restrict__ in, const int* __restrict__ bsum,
                      int* __restrict__ out, int n)
{
    __shared__ int s[256];
    const int b = blockIdx.x, t = threadIdx.x;
    const int base = b * 1024;
    int loc[4];
    int v = 0;
#pragma unroll
    for (int i = 0; i < 4; i++) {
        int idx = base + t * 4 + i;
        int x = (idx < n) ? in[idx] : 0;
        loc[i] = v; v += x;
    }
    s[t] = v; __syncthreads();
    for (int off = 1; off < 256; off <<= 1) {
        int x = (t >= off) ? s[t - off] : 0;
        __syncthreads();
        s[t] += x;
        __syncthreads();
    }
    const int add = bsum[b] + (s[t] - v);
#pragma unroll
    for (int i = 0; i < 4; i++) {
        int idx = base + t * 4 + i;
        if (idx < n) out[idx] = add + loc[i];
    }
}

// ---------------------------------------------------------------------------
// both CSR fills in one pass — exact round-2 measured-good form (plain
// stores; independent aoff/goff reads feed the atomic chain MLP).
// ---------------------------------------------------------------------------
__global__ void fill_both(const int* __restrict__ src, const int* __restrict__ dst,
                          const int* __restrict__ et,
                          const int* __restrict__ aoff, int* __restrict__ acur,
                          int* __restrict__ acsr,
                          const int* __restrict__ goff, int* __restrict__ gcur,
                          int* __restrict__ gcsr, int E)
{
    int e0 = (blockIdx.x * 256 + threadIdx.x) * 4;
#pragma unroll
    for (int j = 0; j < 4; j++) {
        int e = e0 + j;
        if (e < E) {
            int s0 = src[e], d0 = dst[e];
            int seg = d0 * RR + et[e];
            int p = aoff[seg] + atomicAdd(&acur[seg], 1);
            acsr[p] = s0;
            int pg = goff[s0] + atomicAdd(&gcur[s0], 1);
            gcsr[pg] = d0;
        }
    }
}

// ---------------------------------------------------------------------------
// gate gather: 16-lane group per node, short8 (16B) row loads — half the
// load instructions / L2 transactions per 256B row vs 32-lane ushort4.
// TAUb[n] = bf16(tanh( mean_out (h[n]-h[dst])^2 ))
// ---------------------------------------------------------------------------
__global__ __launch_bounds__(256) void gate_gather(
    const ushort* __restrict__ Hc, const int* __restrict__ gcsr,
    const int* __restrict__ goff, const int* __restrict__ deg,
    ushort* __restrict__ TAUb, int N)
{
    const int g = threadIdx.x >> 4, lane = threadIdx.x & 15;
    const int n = blockIdx.x * 16 + g;
    if (n >= N) return;
    const int start = goff[n];
    const int c = deg[n];
    const ushort* hbase = Hc + lane * 8;
    const short8 a8 = *(const short8*)(hbase + (size_t)n * 128);
    float av[8];
#pragma unroll
    for (int j = 0; j < 8; j++) av[j] = b2f((ushort)a8[j]);
    float acc[8];
#pragma unroll
    for (int j = 0; j < 8; j++) acc[j] = 0.f;

    int i = 0;
    for (; i + 4 <= c; i += 4) {
        int d0 = gcsr[start + i],     d1 = gcsr[start + i + 1];
        int d2 = gcsr[start + i + 2], d3 = gcsr[start + i + 3];
        short8 b0 = *(const short8*)(hbase + (size_t)d0 * 128);
        short8 b1 = *(const short8*)(hbase + (size_t)d1 * 128);
        short8 b2 = *(const short8*)(hbase + (size_t)d2 * 128);
        short8 b3 = *(const short8*)(hbase + (size_t)d3 * 128);
#pragma unroll
        for (int j = 0; j < 8; j++) {
            float dx0 = av[j] - b2f((ushort)b0[j]);
            float dx1 = av[j] - b2f((ushort)b1[j]);
            float dx2 = av[j] - b2f((ushort)b2[j]);
            float dx3 = av[j] - b2f((ushort)b3[j]);
            acc[j] += dx0 * dx0 + dx1 * dx1 + dx2 * dx2 + dx3 * dx3;
        }
    }
    if (i + 2 <= c) {
        int d0 = gcsr[start + i], d1 = gcsr[start + i + 1];
        short8 b0 = *(const short8*)(hbase + (size_t)d0 * 128);
        short8 b1 = *(const short8*)(hbase + (size_t)d1 * 128);
#pragma unroll
        for (int j = 0; j < 8; j++) {
            float dx0 = av[j] - b2f((ushort)b0[j]);
            float dx1 = av[j] - b2f((ushort)b1[j]);
            acc[j] += dx0 * dx0 + dx1 * dx1;
        }
        i += 2;
    }
    if (i < c) {
        int d0 = gcsr[start + i];
        short8 b0 = *(const short8*)(hbase + (size_t)d0 * 128);
#pragma unroll
        for (int j = 0; j < 8; j++) {
            float dx0 = av[j] - b2f((ushort)b0[j]);
            acc[j] += dx0 * dx0;
        }
    }
    const float inv = (c > 0) ? (1.f / (float)c) : 1.f;
    short8 t;
#pragma unroll
    for (int j = 0; j < 8; j++) t[j] = (short)f2b(tanhf(acc[j] * inv));
    *(short8*)(TAUb + (size_t)n * D + lane * 8) = t;
}

// ---------------------------------------------------------------------------
// agg gather, NODE-per-group, 16-lane groups + short8 (16B) row loads.
// One group walks all 8 relation segments of node n (contiguous in acsr).
// ---------------------------------------------------------------------------
__global__ __launch_bounds__(256) void agg_gather(
    ushort* __restrict__ Agg, const ushort* __restrict__ Hc,
    const int* __restrict__ acsr, const int* __restrict__ aoff,
    const int* __restrict__ cnt, int N)
{
    const int g = threadIdx.x >> 4, lane = threadIdx.x & 15;
    const int n = blockIdx.x * 16 + g;
    if (n >= N) return;
    const int sbase = n * RR;
    int idx = aoff[sbase];                 // node's edges contiguous from here
    const ushort* hbase = Hc + lane * 8;
    ushort* obase = Agg + (size_t)n * 1024 + lane * 8;

    for (int r = 0; r < RR; r++) {
        const int c = cnt[sbase + r];
        short8 outv = {0, 0, 0, 0, 0, 0, 0, 0};
        if (c > 0) {
            float acc[8];
#pragma unroll
            for (int j = 0; j < 8; j++) acc[j] = 0.f;
            int i = 0;
            for (; i + 4 <= c; i += 4) {
                int s0 = acsr[idx + i],     s1 = acsr[idx + i + 1];
                int s2 = acsr[idx + i + 2], s3 = acsr[idx + i + 3];
                short8 y0 = *(const short8*)(hbase + (size_t)s0 * 128);
                short8 y1 = *(const short8*)(hbase + (size_t)s1 * 128);
                short8 y2 = *(const short8*)(hbase + (size_t)s2 * 128);
                short8 y3 = *(const short8*)(hbase + (size_t)s3 * 128);
#pragma unroll
                for (int j = 0; j < 8; j++)
                    acc[j] += (b2f((ushort)y0[j]) + b2f((ushort)y1[j]))
                            + (b2f((ushort)y2[j]) + b2f((ushort)y3[j]));
            }
            if (i + 2 <= c) {
                int s0 = acsr[idx + i], s1 = acsr[idx + i + 1];
                short8 y0 = *(const short8*)(hbase + (size_t)s0 * 128);
                short8 y1 = *(const short8*)(hbase + (size_t)s1 * 128);
#pragma unroll
                for (int j = 0; j < 8; j++)
                    acc[j] += b2f((ushort)y0[j]) + b2f((ushort)y1[j]);
                i += 2;
            }
            if (i < c) {
                int s0 = acsr[idx + i];
                short8 y0 = *(const short8*)(hbase + (size_t)s0 * 128);
#pragma unroll
                for (int j = 0; j < 8; j++)
                    acc[j] += b2f((ushort)y0[j]);
            }
            const float inv = 1.f / (float)c;
#pragma unroll
            for (int j = 0; j < 8; j++) outv[j] = (short)f2b(acc[j] * inv);
            idx += c;
        }
        __builtin_nontemporal_store(outv, (short8*)(obase + r * 128));
    }
}

// ---------------------------------------------------------------------------
// h_next = (1-tau)*h + tau*hn  (hn already relu'd by GEMM epilogue);
// writes fp32 hn and compact bf16 Hc
// ---------------------------------------------------------------------------
__global__ void finalize(const float* __restrict__ hp, float* __restrict__ hn,
                         const ushort* __restrict__ TAUb, ushort* __restrict__ Hc,
                         int total4)
{
    int idx = blockIdx.x * 256 + threadIdx.x;
    if (idx >= total4) return;
    const float4 p = ((const float4*)hp)[idx];
    const float4 a = ((const float4*)hn)[idx];
    const ushort4 t4 = ((const ushort4*)TAUb)[idx];
    float4 o;
    o.x = p.x + b2f(t4.x) * (a.x - p.x);
    o.y = p.y + b2f(t4.y) * (a.y - p.y);
    o.z = p.z + b2f(t4.z) * (a.z - p.z);
    o.w = p.w + b2f(t4.w) * (a.w - p.w);
    ((float4*)hn)[idx] = o;
    ushort4 ob = { f2b(o.x), f2b(o.y), f2b(o.z), f2b(o.w) };
    *(ushort4*)(Hc + (size_t)idx * 4) = ob;
}

// ---------------------------------------------------------------------------
extern "C" void kernel_launch(void* const* d_in, const int* in_sizes, int n_in,
                              void* d_out, int out_size, void* d_ws, size_t ws_size,
                              hipStream_t stream)
{
    const float* x      = (const float*)d_in[0];
    const int*   src    = (const int*)  d_in[1];
    const int*   dst    = (const int*)  d_in[2];
    const int*   etyp   = (const int*)  d_in[3];
    const float* projW  = (const float*)d_in[4];
    const float* projb  = (const float*)d_in[5];
    const float* basis1 = (const float*)d_in[6];
    const float* comp1  = (const float*)d_in[7];
    const float* root1  = (const float*)d_in[8];
    const float* bias1  = (const float*)d_in[9];
    const float* basis2 = (const float*)d_in[10];
    const float* comp2  = (const float*)d_in[11];
    const float* root2  = (const float*)d_in[12];
    const float* bias2  = (const float*)d_in[13];
    const float* outW   = (const float*)d_in[14];
    const float* outb   = (const float*)d_in[15];

    const int N    = in_sizes[0] / D;
    const int E    = in_sizes[1];
    const int OUTD = in_sizes[15];

    float* out  = (float*)d_out;
    float* lat0 = out + (size_t)N * OUTD;
    float* lat1 = lat0 + (size_t)N * D;
    float* lat2 = lat1 + (size_t)N * D;

    // ---- workspace layout ----
    char* p = (char*)d_ws;
    ushort* Agg   = (ushort*)p;  p += (size_t)N * 1024 * 2;   // [N][8*128] bf16
    ushort* Hc    = (ushort*)p;  p += (size_t)N * 128 * 2;    // [N][128] bf16 (compact h)
    ushort* TAUb  = (ushort*)p;  p += (size_t)N * D * 2;
    ushort* projWT = (ushort*)p; p += 16384 * 2;
    ushort* outWT  = (ushort*)p; p += 16384 * 2;
    ushort* bigBT1 = (ushort*)p; p += (size_t)128 * 1152 * 2;
    ushort* bigBT2 = (ushort*)p; p += (size_t)128 * 1152 * 2;
    int* cnt_i  = (int*)p;       p += (size_t)N * RR * 4;
    int* deg_i  = (int*)p;       p += (size_t)N * 4;
    int* acur   = (int*)p;       p += (size_t)N * RR * 4;
    int* gcur   = (int*)p;       p += (size_t)N * 4;
    int* aoff   = (int*)p;       p += (size_t)N * RR * 4;
    int* goff   = (int*)p;       p += (size_t)N * 4;
    int* acsr   = (int*)p;       p += (size_t)E * 4;
    int* gcsr   = (int*)p;       p += (size_t)E * 4;
    int* bsum   = (int*)p;       p += 4096;

    if ((size_t)(p - (char*)d_ws) > ws_size) return;  // fails loudly

    // zero counters (cnt_i, deg_i, acur, gcur contiguous)
    hipMemsetAsync(cnt_i, 0, sizeof(int) * 2 * ((size_t)N * RR + N), stream);

    // weight prep
    build_bigBT<<<(128 * 1152 + 255) / 256, 256, 0, stream>>>(basis1, comp1, root1, bigBT1);
    build_bigBT<<<(128 * 1152 + 255) / 256, 256, 0, stream>>>(basis2, comp2, root2, bigBT2);
    transpose_pad<<<64, 256, 0, stream>>>(projW, projWT, 128);
    transpose_pad<<<64, 256, 0, stream>>>(outW, outWT, OUTD);

    cast_x<<<(N * 32 + 255) / 256, 256, 0, stream>>>(x, Hc, N * 32);

    count_edges<<<(E / 4 + 255) / 256, 256, 0, stream>>>(src, dst, etyp, cnt_i, deg_i, E);

    {   // exclusive scans -> CSR offsets
        int n1 = N * RR, nb1 = (n1 + 1023) / 1024;
        scan1<<<nb1, 256, 0, stream>>>(cnt_i, bsum, n1);
        scan_top<<<1, 1024, 0, stream>>>(bsum, nb1);
        scan2<<<nb1, 256, 0, stream>>>(cnt_i, bsum, aoff, n1);
        int nb2 = (N + 1023) / 1024;
        scan1<<<nb2, 256, 0, stream>>>(deg_i, bsum, N);
        scan_top<<<1, 1024, 0, stream>>>(bsum, nb2);
        scan2<<<nb2, 256, 0, stream>>>(deg_i, bsum, goff, N);
    }

    fill_both<<<(E / 4 + 255) / 256, 256, 0, stream>>>(
        src, dst, etyp, aoff, acur, acsr, goff, gcur, gcsr, E);

    const int mb = (N + 127) / 128;
    const int nodeblocks16 = (N + 15) / 16;

    // proj: lat0 = relu(x @ projW + projb); bf16 -> Hc (in-place safe)
    gemm_bf16<true, true, true, true><<<mb, 256, 0, stream>>>(
        Hc, 128, 2, Hc, 128, projWT, 1, projb, lat0, 128, Hc, 128, N, 128);

    const ushort* bigBT[2] = {bigBT1, bigBT2};
    const float* biases[2] = {bias1, bias2};
    float* lats[3]         = {lat0, lat1, lat2};

    for (int l = 0; l < 2; l++) {
        float* hn = lats[l + 1];

        gate_gather<<<nodeblocks16, 256, 0, stream>>>(Hc, gcsr, goff, deg_i, TAUb, N);
        agg_gather<<<nodeblocks16, 256, 0, stream>>>(Agg, Hc, acsr, aoff, cnt_i, N);

        // hn = relu([Agg | Hc] @ [W_1..W_8; root] + bias)
        gemm_bf16<true, true, true, false><<<mb, 256, 0, stream>>>(
            Agg, 1024, 16, Hc, 128, bigBT[l], 9, biases[l], hn, 128, nullptr, 0, N, 128);

        finalize<<<(N * 32 + 255) / 256, 256, 0, stream>>>(
            lats[l], hn, TAUb, Hc, N * 32);
    }

    // out = lat2 @ outW + outb
    gemm_bf16<true, false, true, false><<<mb, 256, 0, stream>>>(
        Hc, 128, 2, Hc, 128, outWT, 1, outb, out, OUTD, nullptr, 0, N, OUTD);
}

// Round 6
// 1050.780 us; speedup vs baseline: 1.2362x; 1.0657x over previous
//
#include <hip/hip_runtime.h>
#include <cstdint>
#include <cstddef>

#define D 128
#define RR 8

typedef __attribute__((ext_vector_type(8))) short short8;
typedef __attribute__((ext_vector_type(4))) float f32x4;

__device__ inline ushort f2b(float x) {
    union { float f; unsigned u; } v; v.f = x;
    unsigned r = v.u + 0x7fff + ((v.u >> 16) & 1);
    return (ushort)(r >> 16);
}
__device__ inline float b2f(ushort u) {
    union { unsigned u; float f; } v; v.u = ((unsigned)u) << 16; return v.f;
}

// async global->LDS, 16B per lane; LDS dest = wave-uniform base + lane*16
__device__ inline void gload_lds16(const ushort* g, ushort* l) {
    __builtin_amdgcn_global_load_lds(
        (const __attribute__((address_space(1))) unsigned int*)g,
        (__attribute__((address_space(3))) unsigned int*)l, 16, 0, 0);
}

// ---------------------------------------------------------------------------
// bf16 MFMA GEMM with SPLIT A: C[M, ncol] = [A0 | A1] @ B (+bias) (+relu)
// (unchanged from round 5 — measured good)
// ---------------------------------------------------------------------------
template<bool BIAS, bool RELU, bool STF, bool STB>
__global__ __launch_bounds__(256, 4) void gemm_bf16(
    const ushort* __restrict__ A0, int lda0, int k0steps,
    const ushort* __restrict__ A1, int lda1,
    const ushort* __restrict__ BT, int ktiles,
    const float* __restrict__ bias, float* __restrict__ Cf, int ldcf,
    ushort* __restrict__ Cb, int ldcb, int M, int ncol)
{
    __shared__ ushort As[128 * 64];
    __shared__ ushort Bs[128 * 64];
    const int tid = threadIdx.x;
    const int m0 = blockIdx.x * 128;
    const int ldb = ktiles * 128;
    const int ksteps = ktiles * 2;          // BK = 64

    const int w = tid >> 6, lane = tid & 63;
    const int wm = (w & 1) * 64, wn = (w >> 1) * 64;
    const int l15 = lane & 15, quad = lane >> 4;

    const ushort* a0p[4];
    const ushort* a1p[4];
    const ushort* bp[4];
#pragma unroll
    for (int it = 0; it < 4; it++) {
        int gi = w * 256 + it * 64 + lane;
        int row = gi >> 3, g = gi & 7;
        int cg = g ^ (row & 7);
        int gr = m0 + row; if (gr > M - 1) gr = M - 1;   // clamp tail
        a0p[it] = A0 + (size_t)gr * lda0 + (cg << 3);
        a1p[it] = A1 + (size_t)gr * lda1 + (cg << 3);
        bp[it]  = BT + (size_t)row * ldb + (cg << 3);    // B rows 0..127 always valid
    }

    f32x4 acc[4][4];
    const f32x4 z4 = {0.f, 0.f, 0.f, 0.f};
#pragma unroll
    for (int i = 0; i < 4; i++)
#pragma unroll
        for (int j = 0; j < 4; j++) acc[i][j] = z4;

    for (int kt = 0; kt < ksteps; kt++) {
        const int ko = kt * 64;
        if (kt < k0steps) {
#pragma unroll
            for (int it = 0; it < 4; it++)
                gload_lds16(a0p[it] + ko, As + w * 2048 + it * 512);
        } else {
            const int ko1 = (kt - k0steps) * 64;
#pragma unroll
            for (int it = 0; it < 4; it++)
                gload_lds16(a1p[it] + ko1, As + w * 2048 + it * 512);
        }
#pragma unroll
        for (int it = 0; it < 4; it++)
            gload_lds16(bp[it] + ko, Bs + w * 2048 + it * 512);
        __syncthreads();   // compiler emits vmcnt(0) drain before barrier

#pragma unroll
        for (int ks = 0; ks < 64; ks += 32) {
            const int q0 = (ks >> 3) + quad;        // k-group 0..7
            short8 af[4], bfr[4];
#pragma unroll
            for (int i = 0; i < 4; i++) {
                int row = wm + i * 16 + l15;
                af[i] = *(const short8*)(&As[row * 64 + ((q0 ^ (row & 7)) << 3)]);
            }
#pragma unroll
            for (int j = 0; j < 4; j++) {
                int row = wn + j * 16 + l15;
                bfr[j] = *(const short8*)(&Bs[row * 64 + ((q0 ^ (row & 7)) << 3)]);
            }
#pragma unroll
            for (int i = 0; i < 4; i++)
#pragma unroll
                for (int j = 0; j < 4; j++)
                    acc[i][j] = __builtin_amdgcn_mfma_f32_16x16x32_bf16(
                        af[i], bfr[j], acc[i][j], 0, 0, 0);
        }
        __syncthreads();
    }

    // epilogue: C[m=quad*4+q][n=l15] per 16x16 frag
#pragma unroll
    for (int i = 0; i < 4; i++) {
#pragma unroll
        for (int q = 0; q < 4; q++) {
            int gm = m0 + wm + i * 16 + quad * 4 + q;
            if (gm >= M) continue;
#pragma unroll
            for (int j = 0; j < 4; j++) {
                int gn = wn + j * 16 + l15;
                if (gn >= ncol) continue;
                float v = acc[i][j][q];
                if (BIAS) v += bias[gn];
                if (RELU) v = v > 0.f ? v : 0.f;
                if (STF) Cf[(size_t)gm * ldcf + gn] = v;
                if (STB) Cb[(size_t)gm * ldcb + gn] = f2b(v);
            }
        }
    }
}

// ---------------------------------------------------------------------------
// bigBT[f][c]: c<1024 -> W_{c>>7}[c&127][f];  c>=1024 -> root[c-1024][f]
// ---------------------------------------------------------------------------
__global__ void build_bigBT(const float* __restrict__ basis,
                            const float* __restrict__ comp,
                            const float* __restrict__ root,
                            ushort* __restrict__ BT)
{
    int i = blockIdx.x * 256 + threadIdx.x;
    if (i >= 128 * 1152) return;
    int f = i / 1152, c = i - f * 1152;
    float a;
    if (c < 1024) {
        int r = c >> 7, d = c & 127;
        a = 0.f;
#pragma unroll
        for (int b = 0; b < 4; b++)
            a += comp[r * 4 + b] * basis[(b * 128 + d) * 128 + f];
    } else {
        a = root[(c - 1024) * 128 + f];
    }
    BT[i] = f2b(a);
}

// out[f*128+k] = bf16(in[k*cols+f]) for f<cols else 0   (in: [128][cols])
__global__ void transpose_pad(const float* __restrict__ in, ushort* __restrict__ out,
                              int cols)
{
    int i = blockIdx.x * 256 + threadIdx.x;
    if (i >= 128 * 128) return;
    int k = i & 127, f = i >> 7;
    out[i] = (f < cols) ? f2b(in[k * cols + f]) : (ushort)0;
}

// x [N][128] fp32 -> compact bf16 Hc [N][128]
__global__ void cast_x(const float* __restrict__ in, ushort* __restrict__ Hc, int total4)
{
    int i = blockIdx.x * 256 + threadIdx.x;
    if (i >= total4) return;
    float4 v = ((const float4*)in)[i];
    ushort4 o = { f2b(v.x), f2b(v.y), f2b(v.z), f2b(v.w) };
    *(ushort4*)(Hc + (size_t)i * 4) = o;
}

// ---------------------------------------------------------------------------
// count pass that ALSO records each edge's slot within its segment (the
// atomicAdd return value) — the fill pass then needs no atomics at all.
// ---------------------------------------------------------------------------
__global__ void count_slot(const int* __restrict__ src, const int* __restrict__ dst,
                           const int* __restrict__ et, int* __restrict__ cnt,
                           int* __restrict__ deg, int* __restrict__ slotA,
                           int* __restrict__ slotG, int E)
{
    int e0 = (blockIdx.x * 256 + threadIdx.x) * 4;
#pragma unroll
    for (int j = 0; j < 4; j++) {
        int e = e0 + j;
        if (e < E) {
            slotA[e] = atomicAdd(&cnt[dst[e] * RR + et[e]], 1);
            slotG[e] = atomicAdd(&deg[src[e]], 1);
        }
    }
}

// ---------------------------------------------------------------------------
// 3-phase exclusive scan (1024 elements per block)
// ---------------------------------------------------------------------------
__global__ void scan1(const int* __restrict__ in, int* __restrict__ bsum, int n)
{
    __shared__ int s[256];
    const int b = blockIdx.x, t = threadIdx.x;
    const int base = b * 1024;
    int v = 0;
#pragma unroll
    for (int i = 0; i < 4; i++) {
        int idx = base + t * 4 + i;
        if (idx < n) v += in[idx];
    }
    s[t] = v; __syncthreads();
    for (int off = 128; off > 0; off >>= 1) {
        if (t < off) s[t] += s[t + off];
        __syncthreads();
    }
    if (t == 0) bsum[b] = s[0];
}

__global__ void scan_top(int* __restrict__ bsum, int nb)
{
    __shared__ int s[1024];
    const int t = threadIdx.x;
    int v = (t < nb) ? bsum[t] : 0;
    s[t] = v; __syncthreads();
    for (int off = 1; off < 1024; off <<= 1) {
        int x = (t >= off) ? s[t - off] : 0;
        __syncthreads();
        s[t] += x;
        __syncthreads();
    }
    if (t < nb) bsum[t] = s[t] - v;   // exclusive
}

__global__ void scan2(const int* __restrict__ in, const int* __restrict__ bsum,
                      int* __restrict__ out, int n)
{
    __shared__ int s[256];
    const int b = blockIdx.x, t = threadIdx.x;
    const int base = b * 1024;
    int loc[4];
    int v = 0;
#pragma unroll
    for (int i = 0; i < 4; i++) {
        int idx = base + t * 4 + i;
        int x = (idx < n) ? in[idx] : 0;
        loc[i] = v; v += x;
    }
    s[t] = v; __syncthreads();
    for (int off = 1; off < 256; off <<= 1) {
        int x = (t >= off) ? s[t - off] : 0;
        __syncthreads();
        s[t] += x;
        __syncthreads();
    }
    const int add = bsum[b] + (s[t] - v);
#pragma unroll
    for (int i = 0; i < 4; i++) {
        int idx = base + t * 4 + i;
        if (idx < n) out[idx] = add + loc[i];
    }
}

// ---------------------------------------------------------------------------
// fill pass with NO atomics: position = scanned offset + pre-recorded slot.
// All loads independent -> full memory-level parallelism.
// ---------------------------------------------------------------------------
__global__ void fill_scatter(const int* __restrict__ src, const int* __restrict__ dst,
                             const int* __restrict__ et,
                             const int* __restrict__ aoff, const int* __restrict__ goff,
                             const int* __restrict__ slotA, const int* __restrict__ slotG,
                             int* __restrict__ acsr, int* __restrict__ gcsr, int E)
{
    int e0 = (blockIdx.x * 256 + threadIdx.x) * 4;
#pragma unroll
    for (int j = 0; j < 4; j++) {
        int e = e0 + j;
        if (e < E) {
            int s0 = src[e], d0 = dst[e];
            acsr[aoff[d0 * RR + et[e]] + slotA[e]] = s0;
            gcsr[goff[s0] + slotG[e]] = d0;
        }
    }
}

// ---------------------------------------------------------------------------
// gate gather: 16-lane group per node, short8 (16B) row loads.
// TAUb[n] = bf16(tanh( mean_out (h[n]-h[dst])^2 ))   (unchanged, measured good)
// ---------------------------------------------------------------------------
__global__ __launch_bounds__(256) void gate_gather(
    const ushort* __restrict__ Hc, const int* __restrict__ gcsr,
    const int* __restrict__ goff, const int* __restrict__ deg,
    ushort* __restrict__ TAUb, int N)
{
    const int g = threadIdx.x >> 4, lane = threadIdx.x & 15;
    const int n = blockIdx.x * 16 + g;
    if (n >= N) return;
    const int start = goff[n];
    const int c = deg[n];
    const ushort* hbase = Hc + lane * 8;
    const short8 a8 = *(const short8*)(hbase + (size_t)n * 128);
    float av[8];
#pragma unroll
    for (int j = 0; j < 8; j++) av[j] = b2f((ushort)a8[j]);
    float acc[8];
#pragma unroll
    for (int j = 0; j < 8; j++) acc[j] = 0.f;

    int i = 0;
    for (; i + 4 <= c; i += 4) {
        int d0 = gcsr[start + i],     d1 = gcsr[start + i + 1];
        int d2 = gcsr[start + i + 2], d3 = gcsr[start + i + 3];
        short8 b0 = *(const short8*)(hbase + (size_t)d0 * 128);
        short8 b1 = *(const short8*)(hbase + (size_t)d1 * 128);
        short8 b2 = *(const short8*)(hbase + (size_t)d2 * 128);
        short8 b3 = *(const short8*)(hbase + (size_t)d3 * 128);
#pragma unroll
        for (int j = 0; j < 8; j++) {
            float dx0 = av[j] - b2f((ushort)b0[j]);
            float dx1 = av[j] - b2f((ushort)b1[j]);
            float dx2 = av[j] - b2f((ushort)b2[j]);
            float dx3 = av[j] - b2f((ushort)b3[j]);
            acc[j] += dx0 * dx0 + dx1 * dx1 + dx2 * dx2 + dx3 * dx3;
        }
    }
    if (i + 2 <= c) {
        int d0 = gcsr[start + i], d1 = gcsr[start + i + 1];
        short8 b0 = *(const short8*)(hbase + (size_t)d0 * 128);
        short8 b1 = *(const short8*)(hbase + (size_t)d1 * 128);
#pragma unroll
        for (int j = 0; j < 8; j++) {
            float dx0 = av[j] - b2f((ushort)b0[j]);
            float dx1 = av[j] - b2f((ushort)b1[j]);
            acc[j] += dx0 * dx0 + dx1 * dx1;
        }
        i += 2;
    }
    if (i < c) {
        int d0 = gcsr[start + i];
        short8 b0 = *(const short8*)(hbase + (size_t)d0 * 128);
#pragma unroll
        for (int j = 0; j < 8; j++) {
            float dx0 = av[j] - b2f((ushort)b0[j]);
            acc[j] += dx0 * dx0;
        }
    }
    const float inv = (c > 0) ? (1.f / (float)c) : 1.f;
    short8 t;
#pragma unroll
    for (int j = 0; j < 8; j++) t[j] = (short)f2b(tanhf(acc[j] * inv));
    *(short8*)(TAUb + (size_t)n * D + lane * 8) = t;
}

// ---------------------------------------------------------------------------
// agg gather, NODE-per-group, DECOUPLED load stream: walk all edges of the
// node 4-wide regardless of relation boundaries (indices contiguous in acsr),
// accumulate cumulative per-feature sums, emit (cum-prev)/c at each boundary.
// Keeps 4 row-loads in flight where segments avg ~2 edges (was ~1 in flight).
// ---------------------------------------------------------------------------
__global__ __launch_bounds__(256) void agg_gather(
    ushort* __restrict__ Agg, const ushort* __restrict__ Hc,
    const int* __restrict__ acsr, const int* __restrict__ aoff,
    const int* __restrict__ cnt, int N)
{
    const int g = threadIdx.x >> 4, lane = threadIdx.x & 15;
    const int n = blockIdx.x * 16 + g;
    if (n >= N) return;
    const int sbase = n * RR;
    const int start = aoff[sbase];         // node's edges contiguous from here
    int ctot = 0;
#pragma unroll
    for (int r0 = 0; r0 < RR; r0++) ctot += cnt[sbase + r0];   // one hot line

    const ushort* hbase = Hc + lane * 8;
    ushort* obase = Agg + (size_t)n * 1024 + lane * 8;

    float cum[8], prev[8];
#pragma unroll
    for (int j = 0; j < 8; j++) { cum[j] = 0.f; prev[j] = 0.f; }
    int r = 0;
    int segstart = 0;
    int nexte = cnt[sbase];                // end of segment 0

    auto flush = [&]() {
        int c = nexte - segstart;
        short8 outv = {0, 0, 0, 0, 0, 0, 0, 0};
        if (c > 0) {
            float inv = 1.f / (float)c;
#pragma unroll
            for (int j = 0; j < 8; j++)
                outv[j] = (short)f2b((cum[j] - prev[j]) * inv);
        }
        __builtin_nontemporal_store(outv, (short8*)(obase + r * 128));
#pragma unroll
        for (int j = 0; j < 8; j++) prev[j] = cum[j];
        segstart = nexte;
        r++;
        if (r < RR) nexte += cnt[sbase + r];
    };

    int i = 0;
    for (; i + 4 <= ctot; i += 4) {
        int s0 = acsr[start + i],     s1 = acsr[start + i + 1];
        int s2 = acsr[start + i + 2], s3 = acsr[start + i + 3];
        short8 y0 = *(const short8*)(hbase + (size_t)s0 * 128);
        short8 y1 = *(const short8*)(hbase + (size_t)s1 * 128);
        short8 y2 = *(const short8*)(hbase + (size_t)s2 * 128);
        short8 y3 = *(const short8*)(hbase + (size_t)s3 * 128);
        while (i >= nexte) flush();
#pragma unroll
        for (int j = 0; j < 8; j++) cum[j] += b2f((ushort)y0[j]);
        while (i + 1 >= nexte) flush();
#pragma unroll
        for (int j = 0; j < 8; j++) cum[j] += b2f((ushort)y1[j]);
        while (i + 2 >= nexte) flush();
#pragma unroll
        for (int j = 0; j < 8; j++) cum[j] += b2f((ushort)y2[j]);
        while (i + 3 >= nexte) flush();
#pragma unroll
        for (int j = 0; j < 8; j++) cum[j] += b2f((ushort)y3[j]);
    }
    for (; i < ctot; i++) {
        int s0 = acsr[start + i];
        short8 y0 = *(const short8*)(hbase + (size_t)s0 * 128);
        while (i >= nexte) flush();
#pragma unroll
        for (int j = 0; j < 8; j++) cum[j] += b2f((ushort)y0[j]);
    }
    while (r < RR) flush();
}

// ---------------------------------------------------------------------------
// h_next = (1-tau)*h + tau*hn  (hn already relu'd by GEMM epilogue);
// writes fp32 hn and compact bf16 Hc
// ---------------------------------------------------------------------------
__global__ void finalize(const float* __restrict__ hp, float* __restrict__ hn,
                         const ushort* __restrict__ TAUb, ushort* __restrict__ Hc,
                         int total4)
{
    int idx = blockIdx.x * 256 + threadIdx.x;
    if (idx >= total4) return;
    const float4 p = ((const float4*)hp)[idx];
    const float4 a = ((const float4*)hn)[idx];
    const ushort4 t4 = ((const ushort4*)TAUb)[idx];
    float4 o;
    o.x = p.x + b2f(t4.x) * (a.x - p.x);
    o.y = p.y + b2f(t4.y) * (a.y - p.y);
    o.z = p.z + b2f(t4.z) * (a.z - p.z);
    o.w = p.w + b2f(t4.w) * (a.w - p.w);
    ((float4*)hn)[idx] = o;
    ushort4 ob = { f2b(o.x), f2b(o.y), f2b(o.z), f2b(o.w) };
    *(ushort4*)(Hc + (size_t)idx * 4) = ob;
}

// ---------------------------------------------------------------------------
extern "C" void kernel_launch(void* const* d_in, const int* in_sizes, int n_in,
                              void* d_out, int out_size, void* d_ws, size_t ws_size,
                              hipStream_t stream)
{
    const float* x      = (const float*)d_in[0];
    const int*   src    = (const int*)  d_in[1];
    const int*   dst    = (const int*)  d_in[2];
    const int*   etyp   = (const int*)  d_in[3];
    const float* projW  = (const float*)d_in[4];
    const float* projb  = (const float*)d_in[5];
    const float* basis1 = (const float*)d_in[6];
    const float* comp1  = (const float*)d_in[7];
    const float* root1  = (const float*)d_in[8];
    const float* bias1  = (const float*)d_in[9];
    const float* basis2 = (const float*)d_in[10];
    const float* comp2  = (const float*)d_in[11];
    const float* root2  = (const float*)d_in[12];
    const float* bias2  = (const float*)d_in[13];
    const float* outW   = (const float*)d_in[14];
    const float* outb   = (const float*)d_in[15];

    const int N    = in_sizes[0] / D;
    const int E    = in_sizes[1];
    const int OUTD = in_sizes[15];

    float* out  = (float*)d_out;
    float* lat0 = out + (size_t)N * OUTD;
    float* lat1 = lat0 + (size_t)N * D;
    float* lat2 = lat1 + (size_t)N * D;

    // ---- workspace layout ----
    char* p = (char*)d_ws;
    ushort* Agg   = (ushort*)p;  p += (size_t)N * 1024 * 2;   // [N][8*128] bf16
    ushort* Hc    = (ushort*)p;  p += (size_t)N * 128 * 2;    // [N][128] bf16 (compact h)
    ushort* TAUb  = (ushort*)p;  p += (size_t)N * D * 2;
    ushort* projWT = (ushort*)p; p += 16384 * 2;
    ushort* outWT  = (ushort*)p; p += 16384 * 2;
    ushort* bigBT1 = (ushort*)p; p += (size_t)128 * 1152 * 2;
    ushort* bigBT2 = (ushort*)p; p += (size_t)128 * 1152 * 2;
    int* cnt_i  = (int*)p;       p += (size_t)N * RR * 4;
    int* deg_i  = (int*)p;       p += (size_t)N * 4;
    int* aoff   = (int*)p;       p += (size_t)N * RR * 4;
    int* goff   = (int*)p;       p += (size_t)N * 4;
    int* slotA  = (int*)p;       p += (size_t)E * 4;
    int* slotG  = (int*)p;       p += (size_t)E * 4;
    int* acsr   = (int*)p;       p += (size_t)E * 4;
    int* gcsr   = (int*)p;       p += (size_t)E * 4;
    int* bsum   = (int*)p;       p += 4096;

    if ((size_t)(p - (char*)d_ws) > ws_size) return;  // fails loudly

    // zero counters (cnt_i, deg_i contiguous)
    hipMemsetAsync(cnt_i, 0, sizeof(int) * ((size_t)N * RR + N), stream);

    // weight prep
    build_bigBT<<<(128 * 1152 + 255) / 256, 256, 0, stream>>>(basis1, comp1, root1, bigBT1);
    build_bigBT<<<(128 * 1152 + 255) / 256, 256, 0, stream>>>(basis2, comp2, root2, bigBT2);
    transpose_pad<<<64, 256, 0, stream>>>(projW, projWT, 128);
    transpose_pad<<<64, 256, 0, stream>>>(outW, outWT, OUTD);

    cast_x<<<(N * 32 + 255) / 256, 256, 0, stream>>>(x, Hc, N * 32);

    count_slot<<<(E / 4 + 255) / 256, 256, 0, stream>>>(
        src, dst, etyp, cnt_i, deg_i, slotA, slotG, E);

    {   // exclusive scans -> CSR offsets
        int n1 = N * RR, nb1 = (n1 + 1023) / 1024;
        scan1<<<nb1, 256, 0, stream>>>(cnt_i, bsum, n1);
        scan_top<<<1, 1024, 0, stream>>>(bsum, nb1);
        scan2<<<nb1, 256, 0, stream>>>(cnt_i, bsum, aoff, n1);
        int nb2 = (N + 1023) / 1024;
        scan1<<<nb2, 256, 0, stream>>>(deg_i, bsum, N);
        scan_top<<<1, 1024, 0, stream>>>(bsum, nb2);
        scan2<<<nb2, 256, 0, stream>>>(deg_i, bsum, goff, N);
    }

    fill_scatter<<<(E / 4 + 255) / 256, 256, 0, stream>>>(
        src, dst, etyp, aoff, goff, slotA, slotG, acsr, gcsr, E);

    const int mb = (N + 127) / 128;
    const int nodeblocks16 = (N + 15) / 16;

    // proj: lat0 = relu(x @ projW + projb); bf16 -> Hc (in-place safe)
    gemm_bf16<true, true, true, true><<<mb, 256, 0, stream>>>(
        Hc, 128, 2, Hc, 128, projWT, 1, projb, lat0, 128, Hc, 128, N, 128);

    const ushort* bigBT[2] = {bigBT1, bigBT2};
    const float* biases[2] = {bias1, bias2};
    float* lats[3]         = {lat0, lat1, lat2};

    for (int l = 0; l < 2; l++) {
        float* hn = lats[l + 1];

        gate_gather<<<nodeblocks16, 256, 0, stream>>>(Hc, gcsr, goff, deg_i, TAUb, N);
        agg_gather<<<nodeblocks16, 256, 0, stream>>>(Agg, Hc, acsr, aoff, cnt_i, N);

        // hn = relu([Agg | Hc] @ [W_1..W_8; root] + bias)
        gemm_bf16<true, true, true, false><<<mb, 256, 0, stream>>>(
            Agg, 1024, 16, Hc, 128, bigBT[l], 9, biases[l], hn, 128, nullptr, 0, N, 128);

        finalize<<<(N * 32 + 255) / 256, 256, 0, stream>>>(
            lats[l], hn, TAUb, Hc, N * 32);
    }

    // out = lat2 @ outW + outb
    gemm_bf16<true, false, true, false><<<mb, 256, 0, stream>>>(
        Hc, 128, 2, Hc, 128, outWT, 1, outb, out, OUTD, nullptr, 0, N, OUTD);
}